// Round 1
// 11112.437 us; speedup vs baseline: 1.1596x; 1.1596x over previous
//
#include <hip/hip_runtime.h>
#include <hip/hip_cooperative_groups.h>
#include <stdint.h>

namespace cg = cooperative_groups;

typedef unsigned short u16;
typedef __bf16 b8v __attribute__((ext_vector_type(8)));
typedef float  f4v __attribute__((ext_vector_type(4)));

#define NB      256
#define NSTAGE  260

// ws layout (fast path)
#define WS_HB16   0UL          // 3*2*64*1024 bf16 = 768 KB
#define WS_INIT16 786432UL     // 3*1024 bf16
#define WS_EMB16  792576UL     // 101*1024 bf16
#define WS_PWG    1048576UL    // GRU swizzled weights: 3*64 tiles * 6 q * 32 KB = 36 MB
#define WS_PWP    38797312UL   // proj swizzled: 64 tiles * 32 KB = 2 MB
#define WS_NEED   40894464UL

#define N_GRU_GRP  2359296     // 3*64*6*2048 16B-groups
#define N_PRJ_GRP  131072      // 64*2048
#define N_EMB_GRP  12928       // 101*1024/8
#define N_TOT_GRP  2503680

__device__ __forceinline__ float sigm(float x) { return 1.0f / (1.0f + __expf(-x)); }
__device__ __forceinline__ float tanh_f(float x) {
  float ax = fabsf(x);
  float e = __expf(-2.0f * ax);
  float m = (1.0f - e) / (1.0f + e);
  return x >= 0.0f ? m : -m;
}
__device__ __forceinline__ u16 f2b(float f) {
  union { float f; uint32_t u; } x; x.f = f;
  uint32_t r = x.u + 0x7fffu + ((x.u >> 16) & 1u);
  return (u16)(r >> 16);
}
__device__ __forceinline__ b8v cvt8(f4v lo, f4v hi) {
  b8v v;
  v[0] = (__bf16)lo[0]; v[1] = (__bf16)lo[1]; v[2] = (__bf16)lo[2]; v[3] = (__bf16)lo[3];
  v[4] = (__bf16)hi[0]; v[5] = (__bf16)hi[1]; v[6] = (__bf16)hi[2]; v[7] = (__bf16)hi[3];
  return v;
}

// ---------- prep: bf16-convert + swizzle weights into per-wave streams ----------
// GRU stream (l,ct,q): q = gate*2+p (gate 0=r,1=z,2=n; p 0=Wih,1=Whh).
// Stream layout: [s(8)][tt(4)][lane(64)] 16B groups; lane=(lq,ln):
//   element j: W[gate*1024 + ct*16 + ln][s*128 + tt*32 + lq*8 + j]
__global__ __launch_bounds__(256) void prep(
    const float* __restrict__ embed, const float* __restrict__ Wih,
    const float* __restrict__ Whh, const float* __restrict__ initS,
    const float* __restrict__ linW, unsigned char* __restrict__ ws)
{
  int idx = blockIdx.x * 256 + threadIdx.x;
  if (idx < N_GRU_GRP) {
    int sid = idx >> 11, w = idx & 2047;
    int q = sid % 6, lct = sid / 6;
    int ct = lct & 63, l = lct >> 6;
    int s = w >> 8, tt = (w >> 6) & 3, lane = w & 63;
    int gate = q >> 1, p = q & 1;
    int row = gate * 1024 + ct * 16 + (lane & 15);
    int k0  = s * 128 + tt * 32 + (lane >> 4) * 8;
    const float* src = (p ? Whh : Wih) + (size_t)l * 3145728 + (size_t)row * 1024 + k0;
    *(b8v*)(ws + WS_PWG + (size_t)idx * 16) =
        cvt8(*(const f4v*)src, *(const f4v*)(src + 4));
  } else if (idx < N_GRU_GRP + N_PRJ_GRP) {
    int i2 = idx - N_GRU_GRP;
    int ct = i2 >> 11, w = i2 & 2047;
    int s = w >> 8, tt = (w >> 6) & 3, lane = w & 63;
    int row = ct * 16 + (lane & 15);
    int k0  = s * 128 + tt * 32 + (lane >> 4) * 8;
    const float* src = linW + (size_t)row * 1024 + k0;
    *(b8v*)(ws + WS_PWP + (size_t)i2 * 16) =
        cvt8(*(const f4v*)src, *(const f4v*)(src + 4));
  } else if (idx < N_GRU_GRP + N_PRJ_GRP + N_EMB_GRP) {
    int i3 = idx - (N_GRU_GRP + N_PRJ_GRP);
    const float* src = embed + (size_t)i3 * 8;
    *(b8v*)(ws + WS_EMB16 + (size_t)i3 * 16) =
        cvt8(*(const f4v*)src, *(const f4v*)(src + 4));
  } else if (idx < N_TOT_GRP) {
    int i4 = idx - (N_GRU_GRP + N_PRJ_GRP + N_EMB_GRP);
    const float* src = initS + (size_t)i4 * 8;
    *(b8v*)(ws + WS_INIT16 + (size_t)i4 * 16) =
        cvt8(*(const f4v*)src, *(const f4v*)(src + 4));
  }
}

// ---------- fast main: weights resident in VGPRs, direct per-lane A-fragment loads ----------
// 4 waves/block split as (part = x|h operand) x (K-half). Each wave: 3 gate-streams,
// 48 weight b8v (192 VGPR), 192 MFMA/stage, 64 A-frag global loads (depth-3 prefetch).
// No LDS staging of activations; ONE __syncthreads per stage for the 12-slot gate reduce.
// LDS = 12*64*20*4 = 61440 B.
__global__ __launch_bounds__(256, 1) void dec_fast(
    const int* __restrict__ y,
    const float* __restrict__ bih, const float* __restrict__ bhh,
    const float* __restrict__ initS, const float* __restrict__ linb,
    float* __restrict__ out, unsigned char* __restrict__ ws)
{
  cg::grid_group grid = cg::this_grid();

  __shared__ __align__(16) float gate_lds[12][64][20];

  const int tid  = threadIdx.x;
  const int bid  = blockIdx.x;
  const int l    = bid >> 6;
  const int ct   = bid & 63;
  const int c0   = ct << 4;
  const int wv   = tid >> 6;
  const int lane = tid & 63;
  const int lq   = lane >> 4;
  const int ln   = lane & 15;
  const int part = wv & 1;   // 0 = x/Wih side, 1 = h/Whh side
  const int kh   = wv >> 1;  // K half (0: k<512, 1: k>=512)

  u16* hb16        = (u16*)(ws + WS_HB16);
  const u16* ini16 = (const u16*)(ws + WS_INIT16);
  const u16* emb16 = (const u16*)(ws + WS_EMB16);

  // ---- persistent weight registers (loaded once) ----
  b8v wreg[3][4][4];
  if (l < 3) {
    const unsigned char* wst = ws + WS_PWG + (size_t)(l * 64 + ct) * 196608;
    #pragma unroll
    for (int g = 0; g < 3; ++g)
      #pragma unroll
      for (int si = 0; si < 4; ++si)
        #pragma unroll
        for (int tt = 0; tt < 4; ++tt)
          wreg[g][si][tt] = *(const b8v*)(wst + (size_t)(g * 2 + part) * 32768
                                              + (size_t)(kh * 4 + si) * 4096
                                              + (size_t)tt * 1024 + (size_t)lane * 16);
  } else {
    // projection: wave wv owns K quarter [wv*256, wv*256+256)
    const unsigned char* wst = ws + WS_PWP + (size_t)ct * 32768;
    #pragma unroll
    for (int si = 0; si < 2; ++si)
      #pragma unroll
      for (int tt = 0; tt < 4; ++tt)
        wreg[0][si][tt] = *(const b8v*)(wst + (size_t)(wv * 2 + si) * 4096
                                            + (size_t)tt * 1024 + (size_t)lane * 16);
  }

  // ---- per-thread epilogue constants ----
  const int eb = tid >> 2;
  const int cc = (tid & 3) << 2;
  const int cg = c0 + cc;
  float hold[4];
  float rb[4], zb[4], ib[4], hbv[4];
  if (l < 3) {
    const float* biL = bih + l * 3072;
    const float* bhL = bhh + l * 3072;
    #pragma unroll
    for (int j = 0; j < 4; ++j) {
      hold[j] = initS[(l << 10) + cg + j];
      rb[j]  = biL[cg + j]        + bhL[cg + j];
      zb[j]  = biL[1024 + cg + j] + bhL[1024 + cg + j];
      ib[j]  = biL[2048 + cg + j];
      hbv[j] = bhL[2048 + cg + j];
    }
  }
  f4v pbias = (f4v){0.f, 0.f, 0.f, 0.f};
  if (l == 3) pbias = *(const f4v*)(linb + cg);

  int tokCur[4] = {100, 100, 100, 100};

  for (int t = 0; t < NSTAGE; ++t) {
    const int u = t - l;
    const bool active = (u >= 0) && (u <= 256);
    const int rp = (t + 1) & 1;
    const int wp = t & 1;
    if (active) {
      if (l < 3) {
        // ---------------- GRU layer ----------------
        const int koff0 = (kh << 9) + (lq << 3);
        const u16* rowp[4];
        if (part == 0) {
          if (l == 0) {
            #pragma unroll
            for (int mi = 0; mi < 4; ++mi)
              rowp[mi] = emb16 + ((size_t)tokCur[mi] << 10) + koff0;
          } else {
            const u16* xb = hb16 + (((l - 1) * 2 + rp) << 16) + koff0;
            #pragma unroll
            for (int mi = 0; mi < 4; ++mi)
              rowp[mi] = xb + ((mi * 16 + ln) << 10);
          }
        } else {
          if (u == 0) {
            const u16* hb = ini16 + (l << 10) + koff0;   // broadcast init row
            #pragma unroll
            for (int mi = 0; mi < 4; ++mi) rowp[mi] = hb;
          } else {
            const u16* hb = hb16 + ((l * 2 + rp) << 16) + koff0;
            #pragma unroll
            for (int mi = 0; mi < 4; ++mi)
              rowp[mi] = hb + ((mi * 16 + ln) << 10);
          }
        }

        // prefetch next stage's tokens (layer-0 x-waves only)
        int tokNext[4];
        const bool wantTok = (l == 0) && (part == 0) && (u < 256);
        if (wantTok) {
          #pragma unroll
          for (int mi = 0; mi < 4; ++mi)
            tokNext[mi] = y[((mi * 16 + ln) << 8) + u];
        }

        f4v acc[3][4];
        #pragma unroll
        for (int g = 0; g < 3; ++g)
          #pragma unroll
          for (int mi = 0; mi < 4; ++mi)
            acc[g][mi] = (f4v){0.f, 0.f, 0.f, 0.f};

        // 8 rounds of 64 K each, depth-3 register prefetch pipeline
        b8v fr[3][2][4];
        #pragma unroll
        for (int rr = 0; rr < 2; ++rr)
          #pragma unroll
          for (int tti = 0; tti < 2; ++tti)
            #pragma unroll
            for (int mi = 0; mi < 4; ++mi)
              fr[rr][tti][mi] = *(const b8v*)(rowp[mi] + rr * 64 + tti * 32);

        #pragma unroll
        for (int r = 0; r < 8; ++r) {
          if (r < 6) {
            #pragma unroll
            for (int tti = 0; tti < 2; ++tti)
              #pragma unroll
              for (int mi = 0; mi < 4; ++mi)
                fr[(r + 2) % 3][tti][mi] =
                    *(const b8v*)(rowp[mi] + (r + 2) * 64 + tti * 32);
          }
          #pragma unroll
          for (int g = 0; g < 3; ++g)
            #pragma unroll
            for (int tti = 0; tti < 2; ++tti)
              #pragma unroll
              for (int mi = 0; mi < 4; ++mi)
                acc[g][mi] = __builtin_amdgcn_mfma_f32_16x16x32_bf16(
                    fr[r % 3][tti][mi], wreg[g][r >> 1][(r & 1) * 2 + tti],
                    acc[g][mi], 0, 0, 0);
        }

        // write 12 partial slots: wave wv -> slots wv*3 + {0:r,1:z,2:n}
        #pragma unroll
        for (int g = 0; g < 3; ++g)
          #pragma unroll
          for (int mi = 0; mi < 4; ++mi)
            #pragma unroll
            for (int r4 = 0; r4 < 4; ++r4)
              gate_lds[wv * 3 + g][mi * 16 + lq * 4 + r4][ln] = acc[g][mi][r4];
        __syncthreads();

        {
          const f4v v0  = *(const f4v*)&gate_lds[0][eb][cc];
          const f4v v1  = *(const f4v*)&gate_lds[1][eb][cc];
          const f4v v2  = *(const f4v*)&gate_lds[2][eb][cc];
          const f4v v3  = *(const f4v*)&gate_lds[3][eb][cc];
          const f4v v4  = *(const f4v*)&gate_lds[4][eb][cc];
          const f4v v5  = *(const f4v*)&gate_lds[5][eb][cc];
          const f4v v6  = *(const f4v*)&gate_lds[6][eb][cc];
          const f4v v7  = *(const f4v*)&gate_lds[7][eb][cc];
          const f4v v8  = *(const f4v*)&gate_lds[8][eb][cc];
          const f4v v9  = *(const f4v*)&gate_lds[9][eb][cc];
          const f4v v10 = *(const f4v*)&gate_lds[10][eb][cc];
          const f4v v11 = *(const f4v*)&gate_lds[11][eb][cc];
          u16 pk[4];
          #pragma unroll
          for (int j = 0; j < 4; ++j) {
            float rg = sigm(v0[j] + v6[j] + v3[j] + v9[j] + rb[j]);
            float zg = sigm(v1[j] + v7[j] + v4[j] + v10[j] + zb[j]);
            float ng = tanh_f(v2[j] + v8[j] + ib[j] + rg * (v5[j] + v11[j] + hbv[j]));
            float hn = (1.0f - zg) * ng + zg * hold[j];
            hold[j] = hn;
            pk[j] = f2b(hn);
          }
          *(ushort4*)(hb16 + ((l * 2 + wp) << 16) + (eb << 10) + cg) =
              make_ushort4(pk[0], pk[1], pk[2], pk[3]);
        }
        if (wantTok) {
          #pragma unroll
          for (int mi = 0; mi < 4; ++mi) tokCur[mi] = tokNext[mi];
        }
      } else {
        // ---------------- output projection ----------------
        const u16* xb = hb16 + ((4 + rp) << 16) + (wv << 8) + (lq << 3);
        const u16* rowp[4];
        #pragma unroll
        for (int mi = 0; mi < 4; ++mi) rowp[mi] = xb + ((mi * 16 + ln) << 10);

        f4v acc[4];
        #pragma unroll
        for (int mi = 0; mi < 4; ++mi) acc[mi] = (f4v){0.f, 0.f, 0.f, 0.f};

        b8v fr[3][2][4];
        #pragma unroll
        for (int rr = 0; rr < 2; ++rr)
          #pragma unroll
          for (int tti = 0; tti < 2; ++tti)
            #pragma unroll
            for (int mi = 0; mi < 4; ++mi)
              fr[rr][tti][mi] = *(const b8v*)(rowp[mi] + rr * 64 + tti * 32);

        #pragma unroll
        for (int r = 0; r < 4; ++r) {
          if (r < 2) {
            #pragma unroll
            for (int tti = 0; tti < 2; ++tti)
              #pragma unroll
              for (int mi = 0; mi < 4; ++mi)
                fr[(r + 2) % 3][tti][mi] =
                    *(const b8v*)(rowp[mi] + (r + 2) * 64 + tti * 32);
          }
          #pragma unroll
          for (int tti = 0; tti < 2; ++tti)
            #pragma unroll
            for (int mi = 0; mi < 4; ++mi)
              acc[mi] = __builtin_amdgcn_mfma_f32_16x16x32_bf16(
                  fr[r % 3][tti][mi], wreg[0][r >> 1][(r & 1) * 2 + tti],
                  acc[mi], 0, 0, 0);
        }

        #pragma unroll
        for (int mi = 0; mi < 4; ++mi)
          #pragma unroll
          for (int r4 = 0; r4 < 4; ++r4)
            gate_lds[wv][mi * 16 + lq * 4 + r4][ln] = acc[mi][r4];
        __syncthreads();

        {
          const f4v s0 = *(const f4v*)&gate_lds[0][eb][cc];
          const f4v s1 = *(const f4v*)&gate_lds[1][eb][cc];
          const f4v s2 = *(const f4v*)&gate_lds[2][eb][cc];
          const f4v s3 = *(const f4v*)&gate_lds[3][eb][cc];
          f4v v = s0 + s1 + s2 + s3 + pbias;
          *(f4v*)(out + (((size_t)(eb * 257 + u)) << 10) + cg) = v;
        }
      }
    }
    grid.sync();
  }
}

// ---------------- slow fallback (round-3 passing kernel) ----------------
__global__ __launch_bounds__(256) void dec_slow(
    const int* __restrict__ y, const float* __restrict__ embed,
    const float* __restrict__ Wih, const float* __restrict__ Whh,
    const float* __restrict__ bih, const float* __restrict__ bhh,
    const float* __restrict__ initS, const float* __restrict__ linW,
    const float* __restrict__ linb, float* __restrict__ out,
    unsigned char* __restrict__ ws)
{
  cg::grid_group grid = cg::this_grid();
  __shared__ b8v a_lds[2048];
  __shared__ float gate_lds[4][64][17];
  __shared__ int tok_lds[64];
  const int tid = threadIdx.x, bid = blockIdx.x;
  const int l = bid >> 6, c0 = (bid & 63) << 4;
  const int wv = tid >> 6, lane = tid & 63, lq = lane >> 4, ln = lane & 15;
  float* hb32 = (float*)ws;
  const int rowoff = (wv == 0) ? c0 : (wv == 1) ? (1024 + c0) : (2048 + c0);
  const size_t wl = (size_t)(l < 3 ? l : 0) * 3072 * 1024;
  const float* WihL = Wih + wl;
  const float* WhhL = Whh + wl;
  for (int t = 0; t < NSTAGE; ++t) {
    const int u = t - l;
    const bool active = (u >= 0) && (u <= 256);
    const int rp = (t + 1) & 1, wp = t & 1;
    if (active) {
      if (l == 0 && tid < 64)
        tok_lds[tid] = (u == 0) ? 100 : y[(tid << 8) + (u - 1)];
      if (l < 3) {
        f4v acc[4];
        #pragma unroll
        for (int mi = 0; mi < 4; ++mi) acc[mi] = (f4v){0.f, 0.f, 0.f, 0.f};
        const float* xbase = (l == 0) ? embed : (hb32 + (((l - 1) * 2 + rp) << 16));
        const float* hbase = hb32 + ((l * 2 + rp) << 16);
        for (int s = 0; s < 8; ++s) {
          __syncthreads();
          #pragma unroll
          for (int i = 0; i < 8; ++i) {
            int g = tid + (i << 8);
            int sec = g >> 10, gg = g & 1023, b = gg & 63, k8 = gg >> 6;
            int koff = (s << 7) + (k8 << 3);
            const float* src;
            if (sec == 0) src = (l == 0) ? embed + ((size_t)tok_lds[b] << 10) + koff
                                         : xbase + (b << 10) + koff;
            else src = (u == 0) ? initS + (l << 10) + koff : hbase + (b << 10) + koff;
            a_lds[((sec << 4) + k8) * 64 + b] = cvt8(*(const f4v*)src, *(const f4v*)(src + 4));
          }
          __syncthreads();
          const int pstart = (wv == 3) ? 1 : 0;
          const int pend = (wv == 2) ? 1 : 2;
          for (int part = pstart; part < pend; ++part) {
            const float* wrow = ((part == 0) ? WihL : WhhL)
                              + (size_t)(rowoff + ln) * 1024 + (s << 7) + (lq << 3);
            #pragma unroll
            for (int tt = 0; tt < 4; ++tt) {
              b8v bf = cvt8(*(const f4v*)(wrow + (tt << 5)), *(const f4v*)(wrow + (tt << 5) + 4));
              int fb = ((part << 4) + (tt << 2) + lq) * 64 + ln;
              #pragma unroll
              for (int mi = 0; mi < 4; ++mi)
                acc[mi] = __builtin_amdgcn_mfma_f32_16x16x32_bf16(a_lds[fb + (mi << 4)], bf, acc[mi], 0, 0, 0);
            }
          }
        }
        #pragma unroll
        for (int mi = 0; mi < 4; ++mi)
          #pragma unroll
          for (int r = 0; r < 4; ++r)
            gate_lds[wv][(mi << 4) + (lq << 2) + r][ln] = acc[mi][r];
        __syncthreads();
        {
          const int b = tid >> 2, cc = (tid & 3) << 2, cg = c0 + cc;
          const float* biL = bih + l * 3072;
          const float* bhL = bhh + l * 3072;
          float hold[4];
          if (u == 0) {
            #pragma unroll
            for (int j = 0; j < 4; ++j) hold[j] = initS[(l << 10) + cg + j];
          } else {
            const float* hp = hb32 + ((size_t)(l * 2 + rp) << 16) + (b << 10) + cg;
            #pragma unroll
            for (int j = 0; j < 4; ++j) hold[j] = hp[j];
          }
          float* o32 = hb32 + ((size_t)(l * 2 + wp) << 16) + (b << 10) + cg;
          #pragma unroll
          for (int j = 0; j < 4; ++j) {
            int c = cg + j;
            float rpre = gate_lds[0][b][cc + j] + biL[c] + bhL[c];
            float zpre = gate_lds[1][b][cc + j] + biL[1024 + c] + bhL[1024 + c];
            float inn = gate_lds[2][b][cc + j] + biL[2048 + c];
            float hnn = gate_lds[3][b][cc + j] + bhL[2048 + c];
            float rg = sigm(rpre), zg = sigm(zpre);
            float ng = tanh_f(inn + rg * hnn);
            o32[j] = (1.0f - zg) * ng + zg * hold[j];
          }
        }
      } else {
        f4v acc1 = (f4v){0.f, 0.f, 0.f, 0.f};
        const float* xbase = hb32 + ((4 + rp) << 16);
        for (int s = 0; s < 8; ++s) {
          __syncthreads();
          #pragma unroll
          for (int i = 0; i < 4; ++i) {
            int g = tid + (i << 8);
            int b = g & 63, k8 = g >> 6;
            const float* src = xbase + (b << 10) + (s << 7) + (k8 << 3);
            a_lds[k8 * 64 + b] = cvt8(*(const f4v*)src, *(const f4v*)(src + 4));
          }
          __syncthreads();
          const float* wrow = linW + (size_t)(c0 + ln) * 1024 + (s << 7) + (lq << 3);
          #pragma unroll
          for (int tt = 0; tt < 4; ++tt) {
            b8v bf = cvt8(*(const f4v*)(wrow + (tt << 5)), *(const f4v*)(wrow + (tt << 5) + 4));
            acc1 = __builtin_amdgcn_mfma_f32_16x16x32_bf16(
                     a_lds[((tt << 2) + lq) * 64 + (wv << 4) + ln], bf, acc1, 0, 0, 0);
          }
        }
        const float bias = linb[c0 + ln];
        #pragma unroll
        for (int r = 0; r < 4; ++r) {
          int b = (wv << 4) + (lq << 2) + r;
          out[((size_t)(b * 257 + u) << 10) + c0 + ln] = acc1[r] + bias;
        }
      }
    }
    grid.sync();
  }
}

extern "C" void kernel_launch(void* const* d_in, const int* in_sizes, int n_in,
                              void* d_out, int out_size, void* d_ws, size_t ws_size,
                              hipStream_t stream) {
  const int* y        = (const int*)d_in[0];
  const float* embed  = (const float*)d_in[2];
  const float* Wih    = (const float*)d_in[3];
  const float* Whh    = (const float*)d_in[4];
  const float* bih    = (const float*)d_in[5];
  const float* bhh    = (const float*)d_in[6];
  const float* initS  = (const float*)d_in[7];
  const float* linW   = (const float*)d_in[8];
  const float* linb   = (const float*)d_in[9];
  float* out = (float*)d_out;
  unsigned char* ws = (unsigned char*)d_ws;

  bool fast_ok = false;
  if (ws_size >= WS_NEED) {
    hipLaunchKernelGGL(prep, dim3(N_TOT_GRP / 256), dim3(256), 0, stream,
                       embed, Wih, Whh, initS, linW, ws);
    void* args[] = {(void*)&y, (void*)&bih, (void*)&bhh, (void*)&initS,
                    (void*)&linb, (void*)&out, (void*)&ws};
    fast_ok = (hipLaunchCooperativeKernel((void*)dec_fast, dim3(NB), dim3(256),
                                          args, 0, stream) == hipSuccess);
  }
  if (!fast_ok) {
    void* args[] = {(void*)&y, (void*)&embed, (void*)&Wih, (void*)&Whh,
                    (void*)&bih, (void*)&bhh, (void*)&initS, (void*)&linW,
                    (void*)&linb, (void*)&out, (void*)&ws};
    hipLaunchCooperativeKernel((void*)dec_slow, dim3(NB), dim3(256), args, 0, stream);
  }
}

// Round 2
// 6081.629 us; speedup vs baseline: 2.1188x; 1.8272x over previous
//
#include <hip/hip_runtime.h>
#include <hip/hip_cooperative_groups.h>
#include <stdint.h>

namespace cg = cooperative_groups;

typedef unsigned short u16;
typedef unsigned long long u64;
typedef __bf16 b8v __attribute__((ext_vector_type(8)));
typedef float  f4v __attribute__((ext_vector_type(4)));

#define NB      256
#define NSTAGE  260

// ws layout (fast path)
#define WS_HB16   0UL          // 3*2*64*1024 bf16 = 768 KB
#define WS_INIT16 786432UL     // 3*1024 bf16
#define WS_EMB16  792576UL     // 101*1024 bf16
#define WS_PWG    1048576UL    // GRU swizzled weights: 3*64 tiles * 6 q * 32 KB = 36 MB
#define WS_PWP    38797312UL   // proj swizzled: 64 tiles * 32 KB = 2 MB
#define WS_CTR    40894464UL   // barrier counter (int)
#define WS_NEED   40894528UL

#define N_GRU_GRP  2359296     // 3*64*6*2048 16B-groups
#define N_PRJ_GRP  131072      // 64*2048
#define N_EMB_GRP  12928       // 101*1024/8
#define N_TOT_GRP  2503680

__device__ __forceinline__ float sigm(float x) { return 1.0f / (1.0f + __expf(-x)); }
__device__ __forceinline__ float tanh_f(float x) {
  float ax = fabsf(x);
  float e = __expf(-2.0f * ax);
  float m = (1.0f - e) / (1.0f + e);
  return x >= 0.0f ? m : -m;
}
__device__ __forceinline__ u16 f2b(float f) {
  union { float f; uint32_t u; } x; x.f = f;
  uint32_t r = x.u + 0x7fffu + ((x.u >> 16) & 1u);
  return (u16)(r >> 16);
}
__device__ __forceinline__ b8v cvt8(f4v lo, f4v hi) {
  b8v v;
  v[0] = (__bf16)lo[0]; v[1] = (__bf16)lo[1]; v[2] = (__bf16)lo[2]; v[3] = (__bf16)lo[3];
  v[4] = (__bf16)hi[0]; v[5] = (__bf16)hi[1]; v[6] = (__bf16)hi[2]; v[7] = (__bf16)hi[3];
  return v;
}

// device-coherent (sc0 sc1) 16B load as 2x relaxed agent-scope 8B atomic loads.
// Bypasses the non-coherent per-XCD L2/L1 -> always reads fresh data at the LLC,
// with NO cache-maintenance fences needed anywhere.
__device__ __forceinline__ b8v aload16(const u16* p) {
  union { u64 q[2]; b8v v; } u;
  u.q[0] = __hip_atomic_load((const u64*)p,       __ATOMIC_RELAXED, __HIP_MEMORY_SCOPE_AGENT);
  u.q[1] = __hip_atomic_load((const u64*)(p + 4), __ATOMIC_RELAXED, __HIP_MEMORY_SCOPE_AGENT);
  return u.v;
}
// device-coherent 8B store (write-through to LLC)
__device__ __forceinline__ void astore8(u16* p, u16 a, u16 b, u16 c, u16 d) {
  union { u16 s[4]; u64 q; } u;
  u.s[0] = a; u.s[1] = b; u.s[2] = c; u.s[3] = d;
  __hip_atomic_store((u64*)p, u.q, __ATOMIC_RELAXED, __HIP_MEMORY_SCOPE_AGENT);
}

// ---------- prep: bf16-convert + swizzle weights into per-wave streams ----------
__global__ __launch_bounds__(256) void prep(
    const float* __restrict__ embed, const float* __restrict__ Wih,
    const float* __restrict__ Whh, const float* __restrict__ initS,
    const float* __restrict__ linW, unsigned char* __restrict__ ws)
{
  int idx = blockIdx.x * 256 + threadIdx.x;
  if (idx == 0) *(int*)(ws + WS_CTR) = 0;   // reset barrier counter every launch
  if (idx < N_GRU_GRP) {
    int sid = idx >> 11, w = idx & 2047;
    int q = sid % 6, lct = sid / 6;
    int ct = lct & 63, l = lct >> 6;
    int s = w >> 8, tt = (w >> 6) & 3, lane = w & 63;
    int gate = q >> 1, p = q & 1;
    int row = gate * 1024 + ct * 16 + (lane & 15);
    int k0  = s * 128 + tt * 32 + (lane >> 4) * 8;
    const float* src = (p ? Whh : Wih) + (size_t)l * 3145728 + (size_t)row * 1024 + k0;
    *(b8v*)(ws + WS_PWG + (size_t)idx * 16) =
        cvt8(*(const f4v*)src, *(const f4v*)(src + 4));
  } else if (idx < N_GRU_GRP + N_PRJ_GRP) {
    int i2 = idx - N_GRU_GRP;
    int ct = i2 >> 11, w = i2 & 2047;
    int s = w >> 8, tt = (w >> 6) & 3, lane = w & 63;
    int row = ct * 16 + (lane & 15);
    int k0  = s * 128 + tt * 32 + (lane >> 4) * 8;
    const float* src = linW + (size_t)row * 1024 + k0;
    *(b8v*)(ws + WS_PWP + (size_t)i2 * 16) =
        cvt8(*(const f4v*)src, *(const f4v*)(src + 4));
  } else if (idx < N_GRU_GRP + N_PRJ_GRP + N_EMB_GRP) {
    int i3 = idx - (N_GRU_GRP + N_PRJ_GRP);
    const float* src = embed + (size_t)i3 * 8;
    *(b8v*)(ws + WS_EMB16 + (size_t)i3 * 16) =
        cvt8(*(const f4v*)src, *(const f4v*)(src + 4));
  } else if (idx < N_TOT_GRP) {
    int i4 = idx - (N_GRU_GRP + N_PRJ_GRP + N_EMB_GRP);
    const float* src = initS + (size_t)i4 * 8;
    *(b8v*)(ws + WS_INIT16 + (size_t)i4 * 16) =
        cvt8(*(const f4v*)src, *(const f4v*)(src + 4));
  }
}

// ---------- fast main ----------
// Weights in VGPRs; A-fragments loaded per-lane direct from the LLC via sc1 atomics;
// custom lightweight device barrier (no L2 writeback/invalidate, unlike grid.sync).
__global__ __launch_bounds__(256, 1) void dec_fast(
    const int* __restrict__ y,
    const float* __restrict__ bih, const float* __restrict__ bhh,
    const float* __restrict__ initS, const float* __restrict__ linb,
    float* __restrict__ out, unsigned char* __restrict__ ws)
{
  __shared__ __align__(16) float gate_lds[12][64][20];

  const int tid  = threadIdx.x;
  const int bid  = blockIdx.x;
  const int l    = bid >> 6;
  const int ct   = bid & 63;
  const int c0   = ct << 4;
  const int wv   = tid >> 6;
  const int lane = tid & 63;
  const int lq   = lane >> 4;
  const int ln   = lane & 15;
  const int part = wv & 1;   // 0 = x/Wih side, 1 = h/Whh side
  const int kh   = wv >> 1;  // K half

  u16* hb16        = (u16*)(ws + WS_HB16);
  const u16* ini16 = (const u16*)(ws + WS_INIT16);
  const u16* emb16 = (const u16*)(ws + WS_EMB16);
  int* bar_ctr     = (int*)(ws + WS_CTR);

  // ---- persistent weight registers (loaded once) ----
  b8v wreg[3][4][4];
  if (l < 3) {
    const unsigned char* wst = ws + WS_PWG + (size_t)(l * 64 + ct) * 196608;
    #pragma unroll
    for (int g = 0; g < 3; ++g)
      #pragma unroll
      for (int si = 0; si < 4; ++si)
        #pragma unroll
        for (int tt = 0; tt < 4; ++tt)
          wreg[g][si][tt] = *(const b8v*)(wst + (size_t)(g * 2 + part) * 32768
                                              + (size_t)(kh * 4 + si) * 4096
                                              + (size_t)tt * 1024 + (size_t)lane * 16);
  } else {
    const unsigned char* wst = ws + WS_PWP + (size_t)ct * 32768;
    #pragma unroll
    for (int si = 0; si < 2; ++si)
      #pragma unroll
      for (int tt = 0; tt < 4; ++tt)
        wreg[0][si][tt] = *(const b8v*)(wst + (size_t)(wv * 2 + si) * 4096
                                            + (size_t)tt * 1024 + (size_t)lane * 16);
  }

  // ---- per-thread epilogue constants ----
  const int eb = tid >> 2;
  const int cc = (tid & 3) << 2;
  const int cg = c0 + cc;
  float hold[4];
  float rb[4], zb[4], ib[4], hbv[4];
  if (l < 3) {
    const float* biL = bih + l * 3072;
    const float* bhL = bhh + l * 3072;
    #pragma unroll
    for (int j = 0; j < 4; ++j) {
      hold[j] = initS[(l << 10) + cg + j];
      rb[j]  = biL[cg + j]        + bhL[cg + j];
      zb[j]  = biL[1024 + cg + j] + bhL[1024 + cg + j];
      ib[j]  = biL[2048 + cg + j];
      hbv[j] = bhL[2048 + cg + j];
    }
  }
  f4v pbias = (f4v){0.f, 0.f, 0.f, 0.f};
  if (l == 3) pbias = *(const f4v*)(linb + cg);

  int tokCur[4] = {100, 100, 100, 100};

  for (int t = 0; t < NSTAGE; ++t) {
    const int u = t - l;
    const bool active = (u >= 0) && (u <= 256);
    const int rp = (t + 1) & 1;
    const int wp = t & 1;
    if (active) {
      if (l < 3) {
        // ---------------- GRU layer ----------------
        const int koff0 = (kh << 9) + (lq << 3);
        const u16* rowp[4];
        if (part == 0) {
          if (l == 0) {
            #pragma unroll
            for (int mi = 0; mi < 4; ++mi)
              rowp[mi] = emb16 + ((size_t)tokCur[mi] << 10) + koff0;
          } else {
            const u16* xb = hb16 + (((l - 1) * 2 + rp) << 16) + koff0;
            #pragma unroll
            for (int mi = 0; mi < 4; ++mi)
              rowp[mi] = xb + ((mi * 16 + ln) << 10);
          }
        } else {
          if (u == 0) {
            const u16* hb = ini16 + (l << 10) + koff0;
            #pragma unroll
            for (int mi = 0; mi < 4; ++mi) rowp[mi] = hb;
          } else {
            const u16* hb = hb16 + ((l * 2 + rp) << 16) + koff0;
            #pragma unroll
            for (int mi = 0; mi < 4; ++mi)
              rowp[mi] = hb + ((mi * 16 + ln) << 10);
          }
        }

        int tokNext[4];
        const bool wantTok = (l == 0) && (part == 0) && (u < 256);
        if (wantTok) {
          #pragma unroll
          for (int mi = 0; mi < 4; ++mi)
            tokNext[mi] = y[((mi * 16 + ln) << 8) + u];
        }

        f4v acc[3][4];
        #pragma unroll
        for (int g = 0; g < 3; ++g)
          #pragma unroll
          for (int mi = 0; mi < 4; ++mi)
            acc[g][mi] = (f4v){0.f, 0.f, 0.f, 0.f};

        b8v fr[3][2][4];
        #pragma unroll
        for (int rr = 0; rr < 2; ++rr)
          #pragma unroll
          for (int tti = 0; tti < 2; ++tti)
            #pragma unroll
            for (int mi = 0; mi < 4; ++mi)
              fr[rr][tti][mi] = aload16(rowp[mi] + rr * 64 + tti * 32);

        #pragma unroll
        for (int r = 0; r < 8; ++r) {
          if (r < 6) {
            #pragma unroll
            for (int tti = 0; tti < 2; ++tti)
              #pragma unroll
              for (int mi = 0; mi < 4; ++mi)
                fr[(r + 2) % 3][tti][mi] = aload16(rowp[mi] + (r + 2) * 64 + tti * 32);
          }
          #pragma unroll
          for (int g = 0; g < 3; ++g)
            #pragma unroll
            for (int tti = 0; tti < 2; ++tti)
              #pragma unroll
              for (int mi = 0; mi < 4; ++mi)
                acc[g][mi] = __builtin_amdgcn_mfma_f32_16x16x32_bf16(
                    fr[r % 3][tti][mi], wreg[g][r >> 1][(r & 1) * 2 + tti],
                    acc[g][mi], 0, 0, 0);
        }

        #pragma unroll
        for (int g = 0; g < 3; ++g)
          #pragma unroll
          for (int mi = 0; mi < 4; ++mi)
            #pragma unroll
            for (int r4 = 0; r4 < 4; ++r4)
              gate_lds[wv * 3 + g][mi * 16 + lq * 4 + r4][ln] = acc[g][mi][r4];
        __syncthreads();

        {
          const f4v v0  = *(const f4v*)&gate_lds[0][eb][cc];
          const f4v v1  = *(const f4v*)&gate_lds[1][eb][cc];
          const f4v v2  = *(const f4v*)&gate_lds[2][eb][cc];
          const f4v v3  = *(const f4v*)&gate_lds[3][eb][cc];
          const f4v v4  = *(const f4v*)&gate_lds[4][eb][cc];
          const f4v v5  = *(const f4v*)&gate_lds[5][eb][cc];
          const f4v v6  = *(const f4v*)&gate_lds[6][eb][cc];
          const f4v v7  = *(const f4v*)&gate_lds[7][eb][cc];
          const f4v v8  = *(const f4v*)&gate_lds[8][eb][cc];
          const f4v v9  = *(const f4v*)&gate_lds[9][eb][cc];
          const f4v v10 = *(const f4v*)&gate_lds[10][eb][cc];
          const f4v v11 = *(const f4v*)&gate_lds[11][eb][cc];
          u16 pk[4];
          #pragma unroll
          for (int j = 0; j < 4; ++j) {
            float rg = sigm(v0[j] + v6[j] + v3[j] + v9[j] + rb[j]);
            float zg = sigm(v1[j] + v7[j] + v4[j] + v10[j] + zb[j]);
            float ng = tanh_f(v2[j] + v8[j] + ib[j] + rg * (v5[j] + v11[j] + hbv[j]));
            float hn = (1.0f - zg) * ng + zg * hold[j];
            hold[j] = hn;
            pk[j] = f2b(hn);
          }
          astore8(hb16 + ((l * 2 + wp) << 16) + (eb << 10) + cg,
                  pk[0], pk[1], pk[2], pk[3]);
        }
        if (wantTok) {
          #pragma unroll
          for (int mi = 0; mi < 4; ++mi) tokCur[mi] = tokNext[mi];
        }
      } else {
        // ---------------- output projection ----------------
        const u16* xb = hb16 + ((4 + rp) << 16) + (wv << 8) + (lq << 3);
        const u16* rowp[4];
        #pragma unroll
        for (int mi = 0; mi < 4; ++mi) rowp[mi] = xb + ((mi * 16 + ln) << 10);

        f4v acc[4];
        #pragma unroll
        for (int mi = 0; mi < 4; ++mi) acc[mi] = (f4v){0.f, 0.f, 0.f, 0.f};

        b8v fr[3][2][4];
        #pragma unroll
        for (int rr = 0; rr < 2; ++rr)
          #pragma unroll
          for (int tti = 0; tti < 2; ++tti)
            #pragma unroll
            for (int mi = 0; mi < 4; ++mi)
              fr[rr][tti][mi] = aload16(rowp[mi] + rr * 64 + tti * 32);

        #pragma unroll
        for (int r = 0; r < 4; ++r) {
          if (r < 2) {
            #pragma unroll
            for (int tti = 0; tti < 2; ++tti)
              #pragma unroll
              for (int mi = 0; mi < 4; ++mi)
                fr[(r + 2) % 3][tti][mi] = aload16(rowp[mi] + (r + 2) * 64 + tti * 32);
          }
          #pragma unroll
          for (int tti = 0; tti < 2; ++tti)
            #pragma unroll
            for (int mi = 0; mi < 4; ++mi)
              acc[mi] = __builtin_amdgcn_mfma_f32_16x16x32_bf16(
                  fr[r % 3][tti][mi], wreg[0][r >> 1][(r & 1) * 2 + tti],
                  acc[mi], 0, 0, 0);
        }

        #pragma unroll
        for (int mi = 0; mi < 4; ++mi)
          #pragma unroll
          for (int r4 = 0; r4 < 4; ++r4)
            gate_lds[wv][mi * 16 + lq * 4 + r4][ln] = acc[mi][r4];
        __syncthreads();

        {
          const f4v s0 = *(const f4v*)&gate_lds[0][eb][cc];
          const f4v s1 = *(const f4v*)&gate_lds[1][eb][cc];
          const f4v s2 = *(const f4v*)&gate_lds[2][eb][cc];
          const f4v s3 = *(const f4v*)&gate_lds[3][eb][cc];
          f4v v = s0 + s1 + s2 + s3 + pbias;
          *(f4v*)(out + (((size_t)(eb * 257 + u)) << 10) + cg) = v;
        }
      }
    }

    // ---- lightweight device barrier: no L2 flush/invalidate ----
    // __syncthreads drains each wave's vmcnt (sc1 stores globally visible),
    // then one relaxed agent-scope fetch_add + spin on a monotonic counter.
    __syncthreads();
    if (tid == 0) {
      int prev = __hip_atomic_fetch_add(bar_ctr, 1, __ATOMIC_RELAXED,
                                        __HIP_MEMORY_SCOPE_AGENT);
      const int target = (t + 1) << 8;
      if (prev + 1 < target) {
        while (__hip_atomic_load(bar_ctr, __ATOMIC_RELAXED,
                                 __HIP_MEMORY_SCOPE_AGENT) < target)
          __builtin_amdgcn_s_sleep(1);
      }
    }
    __syncthreads();
  }
}

// ---------------- slow fallback (round-3 passing kernel) ----------------
__global__ __launch_bounds__(256) void dec_slow(
    const int* __restrict__ y, const float* __restrict__ embed,
    const float* __restrict__ Wih, const float* __restrict__ Whh,
    const float* __restrict__ bih, const float* __restrict__ bhh,
    const float* __restrict__ initS, const float* __restrict__ linW,
    const float* __restrict__ linb, float* __restrict__ out,
    unsigned char* __restrict__ ws)
{
  cg::grid_group grid = cg::this_grid();
  __shared__ b8v a_lds[2048];
  __shared__ float gate_lds[4][64][17];
  __shared__ int tok_lds[64];
  const int tid = threadIdx.x, bid = blockIdx.x;
  const int l = bid >> 6, c0 = (bid & 63) << 4;
  const int wv = tid >> 6, lane = tid & 63, lq = lane >> 4, ln = lane & 15;
  float* hb32 = (float*)ws;
  const int rowoff = (wv == 0) ? c0 : (wv == 1) ? (1024 + c0) : (2048 + c0);
  const size_t wl = (size_t)(l < 3 ? l : 0) * 3072 * 1024;
  const float* WihL = Wih + wl;
  const float* WhhL = Whh + wl;
  for (int t = 0; t < NSTAGE; ++t) {
    const int u = t - l;
    const bool active = (u >= 0) && (u <= 256);
    const int rp = (t + 1) & 1, wp = t & 1;
    if (active) {
      if (l == 0 && tid < 64)
        tok_lds[tid] = (u == 0) ? 100 : y[(tid << 8) + (u - 1)];
      if (l < 3) {
        f4v acc[4];
        #pragma unroll
        for (int mi = 0; mi < 4; ++mi) acc[mi] = (f4v){0.f, 0.f, 0.f, 0.f};
        const float* xbase = (l == 0) ? embed : (hb32 + (((l - 1) * 2 + rp) << 16));
        const float* hbase = hb32 + ((l * 2 + rp) << 16);
        for (int s = 0; s < 8; ++s) {
          __syncthreads();
          #pragma unroll
          for (int i = 0; i < 8; ++i) {
            int g = tid + (i << 8);
            int sec = g >> 10, gg = g & 1023, b = gg & 63, k8 = gg >> 6;
            int koff = (s << 7) + (k8 << 3);
            const float* src;
            if (sec == 0) src = (l == 0) ? embed + ((size_t)tok_lds[b] << 10) + koff
                                         : xbase + (b << 10) + koff;
            else src = (u == 0) ? initS + (l << 10) + koff : hbase + (b << 10) + koff;
            a_lds[((sec << 4) + k8) * 64 + b] = cvt8(*(const f4v*)src, *(const f4v*)(src + 4));
          }
          __syncthreads();
          const int pstart = (wv == 3) ? 1 : 0;
          const int pend = (wv == 2) ? 1 : 2;
          for (int part = pstart; part < pend; ++part) {
            const float* wrow = ((part == 0) ? WihL : WhhL)
                              + (size_t)(rowoff + ln) * 1024 + (s << 7) + (lq << 3);
            #pragma unroll
            for (int tt = 0; tt < 4; ++tt) {
              b8v bf = cvt8(*(const f4v*)(wrow + (tt << 5)), *(const f4v*)(wrow + (tt << 5) + 4));
              int fb = ((part << 4) + (tt << 2) + lq) * 64 + ln;
              #pragma unroll
              for (int mi = 0; mi < 4; ++mi)
                acc[mi] = __builtin_amdgcn_mfma_f32_16x16x32_bf16(a_lds[fb + (mi << 4)], bf, acc[mi], 0, 0, 0);
            }
          }
        }
        #pragma unroll
        for (int mi = 0; mi < 4; ++mi)
          #pragma unroll
          for (int r = 0; r < 4; ++r)
            gate_lds[wv][(mi << 4) + (lq << 2) + r][ln] = acc[mi][r];
        __syncthreads();
        {
          const int b = tid >> 2, cc = (tid & 3) << 2, cg = c0 + cc;
          const float* biL = bih + l * 3072;
          const float* bhL = bhh + l * 3072;
          float hold[4];
          if (u == 0) {
            #pragma unroll
            for (int j = 0; j < 4; ++j) hold[j] = initS[(l << 10) + cg + j];
          } else {
            const float* hp = hb32 + ((size_t)(l * 2 + rp) << 16) + (b << 10) + cg;
            #pragma unroll
            for (int j = 0; j < 4; ++j) hold[j] = hp[j];
          }
          float* o32 = hb32 + ((size_t)(l * 2 + wp) << 16) + (b << 10) + cg;
          #pragma unroll
          for (int j = 0; j < 4; ++j) {
            int c = cg + j;
            float rpre = gate_lds[0][b][cc + j] + biL[c] + bhL[c];
            float zpre = gate_lds[1][b][cc + j] + biL[1024 + c] + bhL[1024 + c];
            float inn = gate_lds[2][b][cc + j] + biL[2048 + c];
            float hnn = gate_lds[3][b][cc + j] + bhL[2048 + c];
            float rg = sigm(rpre), zg = sigm(zpre);
            float ng = tanh_f(inn + rg * hnn);
            o32[j] = (1.0f - zg) * ng + zg * hold[j];
          }
        }
      } else {
        f4v acc1 = (f4v){0.f, 0.f, 0.f, 0.f};
        const float* xbase = hb32 + ((4 + rp) << 16);
        for (int s = 0; s < 8; ++s) {
          __syncthreads();
          #pragma unroll
          for (int i = 0; i < 4; ++i) {
            int g = tid + (i << 8);
            int b = g & 63, k8 = g >> 6;
            const float* src = xbase + (b << 10) + (s << 7) + (k8 << 3);
            a_lds[k8 * 64 + b] = cvt8(*(const f4v*)src, *(const f4v*)(src + 4));
          }
          __syncthreads();
          const float* wrow = linW + (size_t)(c0 + ln) * 1024 + (s << 7) + (lq << 3);
          #pragma unroll
          for (int tt = 0; tt < 4; ++tt) {
            b8v bf = cvt8(*(const f4v*)(wrow + (tt << 5)), *(const f4v*)(wrow + (tt << 5) + 4));
            acc1 = __builtin_amdgcn_mfma_f32_16x16x32_bf16(
                     a_lds[((tt << 2) + lq) * 64 + (wv << 4) + ln], bf, acc1, 0, 0, 0);
          }
        }
        const float bias = linb[c0 + ln];
        #pragma unroll
        for (int r = 0; r < 4; ++r) {
          int b = (wv << 4) + (lq << 2) + r;
          out[((size_t)(b * 257 + u) << 10) + c0 + ln] = acc1[r] + bias;
        }
      }
    }
    grid.sync();
  }
}

extern "C" void kernel_launch(void* const* d_in, const int* in_sizes, int n_in,
                              void* d_out, int out_size, void* d_ws, size_t ws_size,
                              hipStream_t stream) {
  const int* y        = (const int*)d_in[0];
  const float* embed  = (const float*)d_in[2];
  const float* Wih    = (const float*)d_in[3];
  const float* Whh    = (const float*)d_in[4];
  const float* bih    = (const float*)d_in[5];
  const float* bhh    = (const float*)d_in[6];
  const float* initS  = (const float*)d_in[7];
  const float* linW   = (const float*)d_in[8];
  const float* linb   = (const float*)d_in[9];
  float* out = (float*)d_out;
  unsigned char* ws = (unsigned char*)d_ws;

  bool fast_ok = false;
  if (ws_size >= WS_NEED) {
    hipLaunchKernelGGL(prep, dim3(N_TOT_GRP / 256 + 1), dim3(256), 0, stream,
                       embed, Wih, Whh, initS, linW, ws);
    void* args[] = {(void*)&y, (void*)&bih, (void*)&bhh, (void*)&initS,
                    (void*)&linb, (void*)&out, (void*)&ws};
    fast_ok = (hipLaunchCooperativeKernel((void*)dec_fast, dim3(NB), dim3(256),
                                          args, 0, stream) == hipSuccess);
  }
  if (!fast_ok) {
    void* args[] = {(void*)&y, (void*)&embed, (void*)&Wih, (void*)&Whh,
                    (void*)&bih, (void*)&bhh, (void*)&initS, (void*)&linW,
                    (void*)&linb, (void*)&out, (void*)&ws};
    hipLaunchCooperativeKernel((void*)dec_slow, dim3(NB), dim3(256), args, 0, stream);
  }
}

// Round 5
// 4532.742 us; speedup vs baseline: 2.8428x; 1.3417x over previous
//
#include <hip/hip_runtime.h>
#include <hip/hip_cooperative_groups.h>
#include <stdint.h>

namespace cg = cooperative_groups;

typedef unsigned short u16;
typedef unsigned long long u64;
typedef __bf16 b8v __attribute__((ext_vector_type(8)));
typedef float  f4v __attribute__((ext_vector_type(4)));

#define NB      256
#define NSTAGE  260

// ws layout (fast path)
#define WS_HB16   0UL          // 3*2*64*1024 bf16 = 768 KB
#define WS_INIT16 786432UL     // 3*1024 bf16
#define WS_EMB16  792576UL     // 101*1024 bf16
#define WS_PWG    1048576UL    // GRU swizzled weights: 3*64 tiles * 6 q * 32 KB = 36 MB
#define WS_PWP    38797312UL   // proj swizzled: 64 tiles * 32 KB = 2 MB
// two-level barrier: 16 arrival lines + 1 global line + 16 release lines (256B apart)
#define WS_ARR    40894464UL
#define WS_GCT    40898560UL
#define WS_REL    40898816UL
#define WS_NEED   40902912UL

#define N_GRU_GRP  2359296     // 3*64*6*2048 16B-groups
#define N_PRJ_GRP  131072      // 64*2048
#define N_EMB_GRP  12928       // 101*1024/8
#define N_TOT_GRP  2503680

__device__ __forceinline__ float sigm(float x) { return 1.0f / (1.0f + __expf(-x)); }
__device__ __forceinline__ float tanh_f(float x) {
  float ax = fabsf(x);
  float e = __expf(-2.0f * ax);
  float m = (1.0f - e) / (1.0f + e);
  return x >= 0.0f ? m : -m;
}
__device__ __forceinline__ u16 f2b(float f) {
  union { float f; uint32_t u; } x; x.f = f;
  uint32_t r = x.u + 0x7fffu + ((x.u >> 16) & 1u);
  return (u16)(r >> 16);
}
__device__ __forceinline__ b8v cvt8(f4v lo, f4v hi) {
  b8v v;
  v[0] = (__bf16)lo[0]; v[1] = (__bf16)lo[1]; v[2] = (__bf16)lo[2]; v[3] = (__bf16)lo[3];
  v[4] = (__bf16)hi[0]; v[5] = (__bf16)hi[1]; v[6] = (__bf16)hi[2]; v[7] = (__bf16)hi[3];
  return v;
}

// device-coherent (sc0 sc1) loads/stores: bypass non-coherent per-XCD caches,
// served at the LLC -> no cache-maintenance fences needed anywhere.
__device__ __forceinline__ b8v aload16(const u16* p) {
  union { u64 q[2]; b8v v; } u;
  u.q[0] = __hip_atomic_load((const u64*)p,       __ATOMIC_RELAXED, __HIP_MEMORY_SCOPE_AGENT);
  u.q[1] = __hip_atomic_load((const u64*)(p + 4), __ATOMIC_RELAXED, __HIP_MEMORY_SCOPE_AGENT);
  return u.v;
}
__device__ __forceinline__ void astore8(u16* p, u16 a, u16 b, u16 c, u16 d) {
  union { u16 s[4]; u64 q; } u;
  u.s[0] = a; u.s[1] = b; u.s[2] = c; u.s[3] = d;
  __hip_atomic_store((u64*)p, u.q, __ATOMIC_RELAXED, __HIP_MEMORY_SCOPE_AGENT);
}
__device__ __forceinline__ int ld_i(const int* p) {
  return __hip_atomic_load(p, __ATOMIC_RELAXED, __HIP_MEMORY_SCOPE_AGENT);
}
__device__ __forceinline__ void st_i(int* p, int v) {
  __hip_atomic_store(p, v, __ATOMIC_RELAXED, __HIP_MEMORY_SCOPE_AGENT);
}

// ---------- prep: bf16-convert + swizzle weights into per-wave streams ----------
__global__ __launch_bounds__(256) void prep(
    const float* __restrict__ embed, const float* __restrict__ Wih,
    const float* __restrict__ Whh, const float* __restrict__ initS,
    const float* __restrict__ linW, unsigned char* __restrict__ ws)
{
  int idx = blockIdx.x * 256 + threadIdx.x;
  if (idx < 33) *(int*)(ws + WS_ARR + (size_t)idx * 256) = 0;  // zero all barrier lines
  if (idx < N_GRU_GRP) {
    int sid = idx >> 11, w = idx & 2047;
    int q = sid % 6, lct = sid / 6;
    int ct = lct & 63, l = lct >> 6;
    int s = w >> 8, tt = (w >> 6) & 3, lane = w & 63;
    int gate = q >> 1, p = q & 1;
    int row = gate * 1024 + ct * 16 + (lane & 15);
    int k0  = s * 128 + tt * 32 + (lane >> 4) * 8;
    const float* src = (p ? Whh : Wih) + (size_t)l * 3145728 + (size_t)row * 1024 + k0;
    *(b8v*)(ws + WS_PWG + (size_t)idx * 16) =
        cvt8(*(const f4v*)src, *(const f4v*)(src + 4));
  } else if (idx < N_GRU_GRP + N_PRJ_GRP) {
    int i2 = idx - N_GRU_GRP;
    int ct = i2 >> 11, w = i2 & 2047;
    int s = w >> 8, tt = (w >> 6) & 3, lane = w & 63;
    int row = ct * 16 + (lane & 15);
    int k0  = s * 128 + tt * 32 + (lane >> 4) * 8;
    const float* src = linW + (size_t)row * 1024 + k0;
    *(b8v*)(ws + WS_PWP + (size_t)i2 * 16) =
        cvt8(*(const f4v*)src, *(const f4v*)(src + 4));
  } else if (idx < N_GRU_GRP + N_PRJ_GRP + N_EMB_GRP) {
    int i3 = idx - (N_GRU_GRP + N_PRJ_GRP);
    const float* src = embed + (size_t)i3 * 8;
    *(b8v*)(ws + WS_EMB16 + (size_t)i3 * 16) =
        cvt8(*(const f4v*)src, *(const f4v*)(src + 4));
  } else if (idx < N_TOT_GRP) {
    int i4 = idx - (N_GRU_GRP + N_PRJ_GRP + N_EMB_GRP);
    const float* src = initS + (size_t)i4 * 8;
    *(b8v*)(ws + WS_INIT16 + (size_t)i4 * 16) =
        cvt8(*(const f4v*)src, *(const f4v*)(src + 4));
  }
}

// ---------- fast main ----------
// Round-4 compute path + two-level tree barrier, unchanged. Launched as a
// REGULAR kernel (no cooperative API): no grid.sync anywhere; co-residency of
// 256 blocks on 256 CUs is guaranteed by occupancy (>=2 blocks/CU capacity),
// and the barrier tolerates any dispatch skew (monotonic counters).
__global__ __launch_bounds__(256, 1) void dec_fast(
    const int* __restrict__ y,
    const float* __restrict__ bih, const float* __restrict__ bhh,
    const float* __restrict__ initS, const float* __restrict__ linb,
    float* __restrict__ out, unsigned char* __restrict__ ws)
{
  __shared__ __align__(16) float gate_lds[12][64][20];

  const int tid  = threadIdx.x;
  const int bid  = blockIdx.x;
  const int l    = bid >> 6;
  const int ct   = bid & 63;
  const int c0   = ct << 4;
  const int wv   = tid >> 6;
  const int lane = tid & 63;
  const int lq   = lane >> 4;
  const int ln   = lane & 15;
  const int part = wv & 1;   // 0 = x/Wih side, 1 = h/Whh side
  const int kh   = wv >> 1;  // K half

  u16* hb16        = (u16*)(ws + WS_HB16);
  const u16* ini16 = (const u16*)(ws + WS_INIT16);
  const u16* emb16 = (const u16*)(ws + WS_EMB16);

  // barrier pointers (group = bid & 15 -> 16 blocks per arrival line)
  int* const myarr = (int*)(ws + WS_ARR + (size_t)(bid & 15) * 256);
  int* const gctr  = (int*)(ws + WS_GCT);
  int* const myrel = (int*)(ws + WS_REL + (size_t)(bid & 15) * 256);
  unsigned char* const relb = ws + WS_REL;

  // ---- persistent weight registers (loaded once) ----
  b8v wreg[3][4][4];
  if (l < 3) {
    const unsigned char* wst = ws + WS_PWG + (size_t)(l * 64 + ct) * 196608;
    #pragma unroll
    for (int g = 0; g < 3; ++g)
      #pragma unroll
      for (int si = 0; si < 4; ++si)
        #pragma unroll
        for (int tt = 0; tt < 4; ++tt)
          wreg[g][si][tt] = *(const b8v*)(wst + (size_t)(g * 2 + part) * 32768
                                              + (size_t)(kh * 4 + si) * 4096
                                              + (size_t)tt * 1024 + (size_t)lane * 16);
  } else {
    const unsigned char* wst = ws + WS_PWP + (size_t)ct * 32768;
    #pragma unroll
    for (int si = 0; si < 2; ++si)
      #pragma unroll
      for (int tt = 0; tt < 4; ++tt)
        wreg[0][si][tt] = *(const b8v*)(wst + (size_t)(wv * 2 + si) * 4096
                                            + (size_t)tt * 1024 + (size_t)lane * 16);
  }

  // ---- per-thread epilogue constants ----
  const int eb = tid >> 2;
  const int cc = (tid & 3) << 2;
  const int cg = c0 + cc;
  float hold[4];
  float rb[4], zb[4], ib[4], hbv[4];
  if (l < 3) {
    const float* biL = bih + l * 3072;
    const float* bhL = bhh + l * 3072;
    #pragma unroll
    for (int j = 0; j < 4; ++j) {
      hold[j] = initS[(l << 10) + cg + j];
      rb[j]  = biL[cg + j]        + bhL[cg + j];
      zb[j]  = biL[1024 + cg + j] + bhL[1024 + cg + j];
      ib[j]  = biL[2048 + cg + j];
      hbv[j] = bhL[2048 + cg + j];
    }
  }
  f4v pbias = (f4v){0.f, 0.f, 0.f, 0.f};
  if (l == 3) pbias = *(const f4v*)(linb + cg);

  int tokCur[4] = {100, 100, 100, 100};

  for (int t = 0; t < NSTAGE; ++t) {
    const int u = t - l;
    const bool active = (u >= 0) && (u <= 256);
    const int rp = (t + 1) & 1;
    const int wp = t & 1;
    if (active) {
      if (l < 3) {
        // ---------------- GRU layer ----------------
        const int koff0 = (kh << 9) + (lq << 3);
        const u16* rowp[4];
        if (part == 0) {
          if (l == 0) {
            #pragma unroll
            for (int mi = 0; mi < 4; ++mi)
              rowp[mi] = emb16 + ((size_t)tokCur[mi] << 10) + koff0;
          } else {
            const u16* xb = hb16 + (((l - 1) * 2 + rp) << 16) + koff0;
            #pragma unroll
            for (int mi = 0; mi < 4; ++mi)
              rowp[mi] = xb + ((mi * 16 + ln) << 10);
          }
        } else {
          if (u == 0) {
            const u16* hb = ini16 + (l << 10) + koff0;
            #pragma unroll
            for (int mi = 0; mi < 4; ++mi) rowp[mi] = hb;
          } else {
            const u16* hb = hb16 + ((l * 2 + rp) << 16) + koff0;
            #pragma unroll
            for (int mi = 0; mi < 4; ++mi)
              rowp[mi] = hb + ((mi * 16 + ln) << 10);
          }
        }

        int tokNext[4];
        const bool wantTok = (l == 0) && (part == 0) && (u < 256);
        if (wantTok) {
          #pragma unroll
          for (int mi = 0; mi < 4; ++mi)
            tokNext[mi] = y[((mi * 16 + ln) << 8) + u];
        }

        f4v acc[3][4];
        #pragma unroll
        for (int g = 0; g < 3; ++g)
          #pragma unroll
          for (int mi = 0; mi < 4; ++mi)
            acc[g][mi] = (f4v){0.f, 0.f, 0.f, 0.f};

        // 8 rounds of 64 K each, depth-3 register prefetch pipeline
        b8v fr[3][2][4];
        #pragma unroll
        for (int rr = 0; rr < 2; ++rr)
          #pragma unroll
          for (int tti = 0; tti < 2; ++tti)
            #pragma unroll
            for (int mi = 0; mi < 4; ++mi)
              fr[rr][tti][mi] = aload16(rowp[mi] + rr * 64 + tti * 32);

        #pragma unroll
        for (int r = 0; r < 8; ++r) {
          if (r < 6) {
            #pragma unroll
            for (int tti = 0; tti < 2; ++tti)
              #pragma unroll
              for (int mi = 0; mi < 4; ++mi)
                fr[(r + 2) % 3][tti][mi] = aload16(rowp[mi] + (r + 2) * 64 + tti * 32);
          }
          #pragma unroll
          for (int g = 0; g < 3; ++g)
            #pragma unroll
            for (int tti = 0; tti < 2; ++tti)
              #pragma unroll
              for (int mi = 0; mi < 4; ++mi)
                acc[g][mi] = __builtin_amdgcn_mfma_f32_16x16x32_bf16(
                    fr[r % 3][tti][mi], wreg[g][r >> 1][(r & 1) * 2 + tti],
                    acc[g][mi], 0, 0, 0);
        }

        #pragma unroll
        for (int g = 0; g < 3; ++g)
          #pragma unroll
          for (int mi = 0; mi < 4; ++mi)
            #pragma unroll
            for (int r4 = 0; r4 < 4; ++r4)
              gate_lds[wv * 3 + g][mi * 16 + lq * 4 + r4][ln] = acc[g][mi][r4];
        __syncthreads();

        {
          const f4v v0  = *(const f4v*)&gate_lds[0][eb][cc];
          const f4v v1  = *(const f4v*)&gate_lds[1][eb][cc];
          const f4v v2  = *(const f4v*)&gate_lds[2][eb][cc];
          const f4v v3  = *(const f4v*)&gate_lds[3][eb][cc];
          const f4v v4  = *(const f4v*)&gate_lds[4][eb][cc];
          const f4v v5  = *(const f4v*)&gate_lds[5][eb][cc];
          const f4v v6  = *(const f4v*)&gate_lds[6][eb][cc];
          const f4v v7  = *(const f4v*)&gate_lds[7][eb][cc];
          const f4v v8  = *(const f4v*)&gate_lds[8][eb][cc];
          const f4v v9  = *(const f4v*)&gate_lds[9][eb][cc];
          const f4v v10 = *(const f4v*)&gate_lds[10][eb][cc];
          const f4v v11 = *(const f4v*)&gate_lds[11][eb][cc];
          u16 pk[4];
          #pragma unroll
          for (int j = 0; j < 4; ++j) {
            float rg = sigm(v0[j] + v6[j] + v3[j] + v9[j] + rb[j]);
            float zg = sigm(v1[j] + v7[j] + v4[j] + v10[j] + zb[j]);
            float ng = tanh_f(v2[j] + v8[j] + ib[j] + rg * (v5[j] + v11[j] + hbv[j]));
            float hn = (1.0f - zg) * ng + zg * hold[j];
            hold[j] = hn;
            pk[j] = f2b(hn);
          }
          astore8(hb16 + ((l * 2 + wp) << 16) + (eb << 10) + cg,
                  pk[0], pk[1], pk[2], pk[3]);
        }
        if (wantTok) {
          #pragma unroll
          for (int mi = 0; mi < 4; ++mi) tokCur[mi] = tokNext[mi];
        }
      } else {
        // ---------------- output projection ----------------
        const u16* xb = hb16 + ((4 + rp) << 16) + (wv << 8) + (lq << 3);
        const u16* rowp[4];
        #pragma unroll
        for (int mi = 0; mi < 4; ++mi) rowp[mi] = xb + ((mi * 16 + ln) << 10);

        f4v acc[4];
        #pragma unroll
        for (int mi = 0; mi < 4; ++mi) acc[mi] = (f4v){0.f, 0.f, 0.f, 0.f};

        b8v fr[3][2][4];
        #pragma unroll
        for (int rr = 0; rr < 2; ++rr)
          #pragma unroll
          for (int tti = 0; tti < 2; ++tti)
            #pragma unroll
            for (int mi = 0; mi < 4; ++mi)
              fr[rr][tti][mi] = aload16(rowp[mi] + rr * 64 + tti * 32);

        #pragma unroll
        for (int r = 0; r < 4; ++r) {
          if (r < 2) {
            #pragma unroll
            for (int tti = 0; tti < 2; ++tti)
              #pragma unroll
              for (int mi = 0; mi < 4; ++mi)
                fr[(r + 2) % 3][tti][mi] = aload16(rowp[mi] + (r + 2) * 64 + tti * 32);
          }
          #pragma unroll
          for (int tti = 0; tti < 2; ++tti)
            #pragma unroll
            for (int mi = 0; mi < 4; ++mi)
              acc[mi] = __builtin_amdgcn_mfma_f32_16x16x32_bf16(
                  fr[r % 3][tti][mi], wreg[0][r >> 1][(r & 1) * 2 + tti],
                  acc[mi], 0, 0, 0);
        }

        #pragma unroll
        for (int mi = 0; mi < 4; ++mi)
          #pragma unroll
          for (int r4 = 0; r4 < 4; ++r4)
            gate_lds[wv][mi * 16 + lq * 4 + r4][ln] = acc[mi][r4];
        __syncthreads();

        {
          const f4v s0 = *(const f4v*)&gate_lds[0][eb][cc];
          const f4v s1 = *(const f4v*)&gate_lds[1][eb][cc];
          const f4v s2 = *(const f4v*)&gate_lds[2][eb][cc];
          const f4v s3 = *(const f4v*)&gate_lds[3][eb][cc];
          f4v v = s0 + s1 + s2 + s3 + pbias;
          *(f4v*)(out + (((size_t)(eb * 257 + u)) << 10) + cg) = v;
        }
      }
    }

    // ---- two-level tree barrier (skip after last stage) ----
    // __syncthreads drains vmcnt -> all sc1 data stores are at the coherence
    // point before the arrival RMW. Counters monotonic; last arriver forwards.
    if (t + 1 < NSTAGE) {
      __syncthreads();
      if (tid == 0) {
        const int tgt = t + 1;
        int old = __hip_atomic_fetch_add(myarr, 1, __ATOMIC_RELAXED,
                                         __HIP_MEMORY_SCOPE_AGENT);
        if (old + 1 == (tgt << 4)) {          // last of my 16-block group
          int gold = __hip_atomic_fetch_add(gctr, 1, __ATOMIC_RELAXED,
                                            __HIP_MEMORY_SCOPE_AGENT);
          if (gold + 1 == (tgt << 4)) {       // last group overall
            #pragma unroll
            for (int r = 0; r < 16; ++r)
              st_i((int*)(relb + (size_t)r * 256), tgt);
          }
        }
        while (ld_i(myrel) < tgt) __builtin_amdgcn_s_sleep(2);
      }
      __syncthreads();
    }
  }
}

// ---------------- slow fallback (round-3 passing kernel) ----------------
__global__ __launch_bounds__(256) void dec_slow(
    const int* __restrict__ y, const float* __restrict__ embed,
    const float* __restrict__ Wih, const float* __restrict__ Whh,
    const float* __restrict__ bih, const float* __restrict__ bhh,
    const float* __restrict__ initS, const float* __restrict__ linW,
    const float* __restrict__ linb, float* __restrict__ out,
    unsigned char* __restrict__ ws)
{
  cg::grid_group grid = cg::this_grid();
  __shared__ b8v a_lds[2048];
  __shared__ float gate_lds[4][64][17];
  __shared__ int tok_lds[64];
  const int tid = threadIdx.x, bid = blockIdx.x;
  const int l = bid >> 6, c0 = (bid & 63) << 4;
  const int wv = tid >> 6, lane = tid & 63, lq = lane >> 4, ln = lane & 15;
  float* hb32 = (float*)ws;
  const int rowoff = (wv == 0) ? c0 : (wv == 1) ? (1024 + c0) : (2048 + c0);
  const size_t wl = (size_t)(l < 3 ? l : 0) * 3072 * 1024;
  const float* WihL = Wih + wl;
  const float* WhhL = Whh + wl;
  for (int t = 0; t < NSTAGE; ++t) {
    const int u = t - l;
    const bool active = (u >= 0) && (u <= 256);
    const int rp = (t + 1) & 1, wp = t & 1;
    if (active) {
      if (l == 0 && tid < 64)
        tok_lds[tid] = (u == 0) ? 100 : y[(tid << 8) + (u - 1)];
      if (l < 3) {
        f4v acc[4];
        #pragma unroll
        for (int mi = 0; mi < 4; ++mi) acc[mi] = (f4v){0.f, 0.f, 0.f, 0.f};
        const float* xbase = (l == 0) ? embed : (hb32 + (((l - 1) * 2 + rp) << 16));
        const float* hbase = hb32 + ((l * 2 + rp) << 16);
        for (int s = 0; s < 8; ++s) {
          __syncthreads();
          #pragma unroll
          for (int i = 0; i < 8; ++i) {
            int g = tid + (i << 8);
            int sec = g >> 10, gg = g & 1023, b = gg & 63, k8 = gg >> 6;
            int koff = (s << 7) + (k8 << 3);
            const float* src;
            if (sec == 0) src = (l == 0) ? embed + ((size_t)tok_lds[b] << 10) + koff
                                         : xbase + (b << 10) + koff;
            else src = (u == 0) ? initS + (l << 10) + koff : hbase + (b << 10) + koff;
            a_lds[((sec << 4) + k8) * 64 + b] = cvt8(*(const f4v*)src, *(const f4v*)(src + 4));
          }
          __syncthreads();
          const int pstart = (wv == 3) ? 1 : 0;
          const int pend = (wv == 2) ? 1 : 2;
          for (int part = pstart; part < pend; ++part) {
            const float* wrow = ((part == 0) ? WihL : WhhL)
                              + (size_t)(rowoff + ln) * 1024 + (s << 7) + (lq << 3);
            #pragma unroll
            for (int tt = 0; tt < 4; ++tt) {
              b8v bf = cvt8(*(const f4v*)(wrow + (tt << 5)), *(const f4v*)(wrow + (tt << 5) + 4));
              int fb = ((part << 4) + (tt << 2) + lq) * 64 + ln;
              #pragma unroll
              for (int mi = 0; mi < 4; ++mi)
                acc[mi] = __builtin_amdgcn_mfma_f32_16x16x32_bf16(a_lds[fb + (mi << 4)], bf, acc[mi], 0, 0, 0);
            }
          }
        }
        #pragma unroll
        for (int mi = 0; mi < 4; ++mi)
          #pragma unroll
          for (int r = 0; r < 4; ++r)
            gate_lds[wv][(mi << 4) + (lq << 2) + r][ln] = acc[mi][r];
        __syncthreads();
        {
          const int b = tid >> 2, cc = (tid & 3) << 2, cg = c0 + cc;
          const float* biL = bih + l * 3072;
          const float* bhL = bhh + l * 3072;
          float hold[4];
          if (u == 0) {
            #pragma unroll
            for (int j = 0; j < 4; ++j) hold[j] = initS[(l << 10) + cg + j];
          } else {
            const float* hp = hb32 + ((size_t)(l * 2 + rp) << 16) + (b << 10) + cg;
            #pragma unroll
            for (int j = 0; j < 4; ++j) hold[j] = hp[j];
          }
          float* o32 = hb32 + ((size_t)(l * 2 + wp) << 16) + (b << 10) + cg;
          #pragma unroll
          for (int j = 0; j < 4; ++j) {
            int c = cg + j;
            float rpre = gate_lds[0][b][cc + j] + biL[c] + bhL[c];
            float zpre = gate_lds[1][b][cc + j] + biL[1024 + c] + bhL[1024 + c];
            float inn = gate_lds[2][b][cc + j] + biL[2048 + c];
            float hnn = gate_lds[3][b][cc + j] + bhL[2048 + c];
            float rg = sigm(rpre), zg = sigm(zpre);
            float ng = tanh_f(inn + rg * hnn);
            o32[j] = (1.0f - zg) * ng + zg * hold[j];
          }
        }
      } else {
        f4v acc1 = (f4v){0.f, 0.f, 0.f, 0.f};
        const float* xbase = hb32 + ((4 + rp) << 16);
        for (int s = 0; s < 8; ++s) {
          __syncthreads();
          #pragma unroll
          for (int i = 0; i < 4; ++i) {
            int g = tid + (i << 8);
            int b = g & 63, k8 = g >> 6;
            const float* src = xbase + (b << 10) + (s << 7) + (k8 << 3);
            a_lds[k8 * 64 + b] = cvt8(*(const f4v*)src, *(const f4v*)(src + 4));
          }
          __syncthreads();
          const float* wrow = linW + (size_t)(c0 + ln) * 1024 + (s << 7) + (lq << 3);
          #pragma unroll
          for (int tt = 0; tt < 4; ++tt) {
            b8v bf = cvt8(*(const f4v*)(wrow + (tt << 5)), *(const f4v*)(wrow + (tt << 5) + 4));
            acc1 = __builtin_amdgcn_mfma_f32_16x16x32_bf16(
                     a_lds[((tt << 2) + lq) * 64 + (wv << 4) + ln], bf, acc1, 0, 0, 0);
          }
        }
        const float bias = linb[c0 + ln];
        #pragma unroll
        for (int r = 0; r < 4; ++r) {
          int b = (wv << 4) + (lq << 2) + r;
          out[((size_t)(b * 257 + u) << 10) + c0 + ln] = acc1[r] + bias;
        }
      }
    }
    grid.sync();
  }
}

extern "C" void kernel_launch(void* const* d_in, const int* in_sizes, int n_in,
                              void* d_out, int out_size, void* d_ws, size_t ws_size,
                              hipStream_t stream) {
  const int* y        = (const int*)d_in[0];
  const float* embed  = (const float*)d_in[2];
  const float* Wih    = (const float*)d_in[3];
  const float* Whh    = (const float*)d_in[4];
  const float* bih    = (const float*)d_in[5];
  const float* bhh    = (const float*)d_in[6];
  const float* initS  = (const float*)d_in[7];
  const float* linW   = (const float*)d_in[8];
  const float* linb   = (const float*)d_in[9];
  float* out = (float*)d_out;
  unsigned char* ws = (unsigned char*)d_ws;

  if (ws_size >= WS_NEED) {
    // Fast path: regular launches only — identical behavior in fresh,
    // capture, and replay modes (no cooperative API anywhere).
    hipLaunchKernelGGL(prep, dim3(N_TOT_GRP / 256), dim3(256), 0, stream,
                       embed, Wih, Whh, initS, linW, ws);
    hipLaunchKernelGGL(dec_fast, dim3(NB), dim3(256), 0, stream,
                       y, bih, bhh, initS, linb, out, ws);
  } else {
    void* args[] = {(void*)&y, (void*)&embed, (void*)&Wih, (void*)&Whh,
                    (void*)&bih, (void*)&bhh, (void*)&initS, (void*)&linW,
                    (void*)&linb, (void*)&out, (void*)&ws};
    hipLaunchCooperativeKernel((void*)dec_slow, dim3(NB), dim3(256), args, 0, stream);
  }
}

// Round 6
// 2815.188 us; speedup vs baseline: 4.5773x; 1.6101x over previous
//
#include <hip/hip_runtime.h>
#include <hip/hip_cooperative_groups.h>
#include <stdint.h>

namespace cg = cooperative_groups;

typedef unsigned short u16;
typedef unsigned long long u64;
typedef __bf16 b8v __attribute__((ext_vector_type(8)));
typedef float  f4v __attribute__((ext_vector_type(4)));

#define NB      256
#define NSTAGE  260

// ws layout (fast path)
#define WS_HB16   0UL          // 3*2*64*1024 bf16 = 768 KB
#define WS_INIT16 786432UL     // 3*1024 bf16
#define WS_EMB16  792576UL     // 101*1024 bf16
#define WS_PWG    1048576UL    // GRU swizzled weights: 3*64 tiles * 6 q * 32 KB = 36 MB
#define WS_PWP    38797312UL   // proj swizzled: 64 tiles * 32 KB = 2 MB
// two-level barrier: 16 arrival lines + 1 global line + 16 release lines (256B apart)
#define WS_ARR    40894464UL
#define WS_GCT    40898560UL
#define WS_REL    40898816UL
#define WS_NEED   40902912UL

#define N_GRU_GRP  2359296     // 3*64*6*2048 16B-groups
#define N_PRJ_GRP  131072      // 64*2048
#define N_EMB_GRP  12928       // 101*1024/8
#define N_TOT_GRP  2503680

__device__ __forceinline__ float sigm(float x) { return 1.0f / (1.0f + __expf(-x)); }
__device__ __forceinline__ float tanh_f(float x) {
  float ax = fabsf(x);
  float e = __expf(-2.0f * ax);
  float m = (1.0f - e) / (1.0f + e);
  return x >= 0.0f ? m : -m;
}
__device__ __forceinline__ u16 f2b(float f) {
  union { float f; uint32_t u; } x; x.f = f;
  uint32_t r = x.u + 0x7fffu + ((x.u >> 16) & 1u);
  return (u16)(r >> 16);
}
__device__ __forceinline__ b8v cvt8(f4v lo, f4v hi) {
  b8v v;
  v[0] = (__bf16)lo[0]; v[1] = (__bf16)lo[1]; v[2] = (__bf16)lo[2]; v[3] = (__bf16)lo[3];
  v[4] = (__bf16)hi[0]; v[5] = (__bf16)hi[1]; v[6] = (__bf16)hi[2]; v[7] = (__bf16)hi[3];
  return v;
}

// Device-coherent 16B load (sc0 sc1 -> bypass L1 + per-XCD L2, served at LLC).
// NO internal waitcnt: caller manages completion via counted s_waitcnt vmcnt(N).
// This keeps many loads in flight (the atomic-load path serialized them).
__device__ __forceinline__ b8v gload16(const u16* p) {
  b8v v;
  asm volatile("global_load_dwordx4 %0, %1, off sc0 sc1"
               : "=&v"(v) : "v"(p));
  return v;
}
// device-coherent 8B store (write-through to LLC)
__device__ __forceinline__ void astore8(u16* p, u16 a, u16 b, u16 c, u16 d) {
  union { u16 s[4]; u64 q; } u;
  u.s[0] = a; u.s[1] = b; u.s[2] = c; u.s[3] = d;
  __hip_atomic_store((u64*)p, u.q, __ATOMIC_RELAXED, __HIP_MEMORY_SCOPE_AGENT);
}
__device__ __forceinline__ int ld_i(const int* p) {
  return __hip_atomic_load(p, __ATOMIC_RELAXED, __HIP_MEMORY_SCOPE_AGENT);
}
__device__ __forceinline__ void st_i(int* p, int v) {
  __hip_atomic_store(p, v, __ATOMIC_RELAXED, __HIP_MEMORY_SCOPE_AGENT);
}

// One GRU K-round: issue round R+2's 8 loads, wait (counted) for round R,
// fence the scheduler, then 24 MFMAs on round R's fragments.
// WN: loads newer than round R at the wait = 16 (R<6), 8 (R==6), 0 (R==7).
// In-order vmcnt retirement makes the count safe even if older loads linger.
template<int R, int WN>
__device__ __forceinline__ void gru_round(
    b8v (&fr)[3][2][4], const u16* const (&rowp)[4],
    const b8v (&wreg)[3][4][4], f4v (&acc)[3][4])
{
  if (R < 6) {
    #pragma unroll
    for (int tti = 0; tti < 2; ++tti)
      #pragma unroll
      for (int mi = 0; mi < 4; ++mi)
        fr[(R + 2) % 3][tti][mi] = gload16(rowp[mi] + (R + 2) * 64 + tti * 32);
  }
  asm volatile("s_waitcnt vmcnt(%0)" :: "n"(WN));
  __builtin_amdgcn_sched_barrier(0);
  #pragma unroll
  for (int g = 0; g < 3; ++g)
    #pragma unroll
    for (int tti = 0; tti < 2; ++tti)
      #pragma unroll
      for (int mi = 0; mi < 4; ++mi)
        acc[g][mi] = __builtin_amdgcn_mfma_f32_16x16x32_bf16(
            fr[R % 3][tti][mi], wreg[g][R >> 1][(R & 1) * 2 + tti],
            acc[g][mi], 0, 0, 0);
}

template<int R, int WN>
__device__ __forceinline__ void prj_round(
    b8v (&fr)[3][2][4], const u16* const (&rowp)[4],
    const b8v (&wreg)[3][4][4], f4v (&acc)[4])
{
  if (R < 2) {
    #pragma unroll
    for (int tti = 0; tti < 2; ++tti)
      #pragma unroll
      for (int mi = 0; mi < 4; ++mi)
        fr[(R + 2) % 3][tti][mi] = gload16(rowp[mi] + (R + 2) * 64 + tti * 32);
  }
  asm volatile("s_waitcnt vmcnt(%0)" :: "n"(WN));
  __builtin_amdgcn_sched_barrier(0);
  #pragma unroll
  for (int tti = 0; tti < 2; ++tti)
    #pragma unroll
    for (int mi = 0; mi < 4; ++mi)
      acc[mi] = __builtin_amdgcn_mfma_f32_16x16x32_bf16(
          fr[R % 3][tti][mi], wreg[0][R >> 1][(R & 1) * 2 + tti],
          acc[mi], 0, 0, 0);
}

// ---------- prep: bf16-convert + swizzle weights into per-wave streams ----------
__global__ __launch_bounds__(256) void prep(
    const float* __restrict__ embed, const float* __restrict__ Wih,
    const float* __restrict__ Whh, const float* __restrict__ initS,
    const float* __restrict__ linW, unsigned char* __restrict__ ws)
{
  int idx = blockIdx.x * 256 + threadIdx.x;
  if (idx < 33) *(int*)(ws + WS_ARR + (size_t)idx * 256) = 0;  // zero all barrier lines
  if (idx < N_GRU_GRP) {
    int sid = idx >> 11, w = idx & 2047;
    int q = sid % 6, lct = sid / 6;
    int ct = lct & 63, l = lct >> 6;
    int s = w >> 8, tt = (w >> 6) & 3, lane = w & 63;
    int gate = q >> 1, p = q & 1;
    int row = gate * 1024 + ct * 16 + (lane & 15);
    int k0  = s * 128 + tt * 32 + (lane >> 4) * 8;
    const float* src = (p ? Whh : Wih) + (size_t)l * 3145728 + (size_t)row * 1024 + k0;
    *(b8v*)(ws + WS_PWG + (size_t)idx * 16) =
        cvt8(*(const f4v*)src, *(const f4v*)(src + 4));
  } else if (idx < N_GRU_GRP + N_PRJ_GRP) {
    int i2 = idx - N_GRU_GRP;
    int ct = i2 >> 11, w = i2 & 2047;
    int s = w >> 8, tt = (w >> 6) & 3, lane = w & 63;
    int row = ct * 16 + (lane & 15);
    int k0  = s * 128 + tt * 32 + (lane >> 4) * 8;
    const float* src = linW + (size_t)row * 1024 + k0;
    *(b8v*)(ws + WS_PWP + (size_t)i2 * 16) =
        cvt8(*(const f4v*)src, *(const f4v*)(src + 4));
  } else if (idx < N_GRU_GRP + N_PRJ_GRP + N_EMB_GRP) {
    int i3 = idx - (N_GRU_GRP + N_PRJ_GRP);
    const float* src = embed + (size_t)i3 * 8;
    *(b8v*)(ws + WS_EMB16 + (size_t)i3 * 16) =
        cvt8(*(const f4v*)src, *(const f4v*)(src + 4));
  } else if (idx < N_TOT_GRP) {
    int i4 = idx - (N_GRU_GRP + N_PRJ_GRP + N_EMB_GRP);
    const float* src = initS + (size_t)i4 * 8;
    *(b8v*)(ws + WS_INIT16 + (size_t)i4 * 16) =
        cvt8(*(const f4v*)src, *(const f4v*)(src + 4));
  }
}

// ---------- fast main ----------
// Round-5 structure; ONLY change: A-fragment loads are inline-asm
// global_load_dwordx4 sc0 sc1 with hand-counted vmcnt waits (true pipelining).
__global__ __launch_bounds__(256, 1) void dec_fast(
    const int* __restrict__ y,
    const float* __restrict__ bih, const float* __restrict__ bhh,
    const float* __restrict__ initS, const float* __restrict__ linb,
    float* __restrict__ out, unsigned char* __restrict__ ws)
{
  __shared__ __align__(16) float gate_lds[12][64][20];

  const int tid  = threadIdx.x;
  const int bid  = blockIdx.x;
  const int l    = bid >> 6;
  const int ct   = bid & 63;
  const int c0   = ct << 4;
  const int wv   = tid >> 6;
  const int lane = tid & 63;
  const int lq   = lane >> 4;
  const int ln   = lane & 15;
  const int part = wv & 1;   // 0 = x/Wih side, 1 = h/Whh side
  const int kh   = wv >> 1;  // K half

  u16* hb16        = (u16*)(ws + WS_HB16);
  const u16* ini16 = (const u16*)(ws + WS_INIT16);
  const u16* emb16 = (const u16*)(ws + WS_EMB16);

  // barrier pointers (group = bid & 15 -> 16 blocks per arrival line)
  int* const myarr = (int*)(ws + WS_ARR + (size_t)(bid & 15) * 256);
  int* const gctr  = (int*)(ws + WS_GCT);
  int* const myrel = (int*)(ws + WS_REL + (size_t)(bid & 15) * 256);
  unsigned char* const relb = ws + WS_REL;

  // ---- persistent weight registers (loaded once) ----
  b8v wreg[3][4][4];
  if (l < 3) {
    const unsigned char* wst = ws + WS_PWG + (size_t)(l * 64 + ct) * 196608;
    #pragma unroll
    for (int g = 0; g < 3; ++g)
      #pragma unroll
      for (int si = 0; si < 4; ++si)
        #pragma unroll
        for (int tt = 0; tt < 4; ++tt)
          wreg[g][si][tt] = *(const b8v*)(wst + (size_t)(g * 2 + part) * 32768
                                              + (size_t)(kh * 4 + si) * 4096
                                              + (size_t)tt * 1024 + (size_t)lane * 16);
  } else {
    const unsigned char* wst = ws + WS_PWP + (size_t)ct * 32768;
    #pragma unroll
    for (int si = 0; si < 2; ++si)
      #pragma unroll
      for (int tt = 0; tt < 4; ++tt)
        wreg[0][si][tt] = *(const b8v*)(wst + (size_t)(wv * 2 + si) * 4096
                                            + (size_t)tt * 1024 + (size_t)lane * 16);
  }

  // ---- per-thread epilogue constants ----
  const int eb = tid >> 2;
  const int cc = (tid & 3) << 2;
  const int cg = c0 + cc;
  float hold[4];
  float rb[4], zb[4], ib[4], hbv[4];
  if (l < 3) {
    const float* biL = bih + l * 3072;
    const float* bhL = bhh + l * 3072;
    #pragma unroll
    for (int j = 0; j < 4; ++j) {
      hold[j] = initS[(l << 10) + cg + j];
      rb[j]  = biL[cg + j]        + bhL[cg + j];
      zb[j]  = biL[1024 + cg + j] + bhL[1024 + cg + j];
      ib[j]  = biL[2048 + cg + j];
      hbv[j] = bhL[2048 + cg + j];
    }
  }
  f4v pbias = (f4v){0.f, 0.f, 0.f, 0.f};
  if (l == 3) pbias = *(const f4v*)(linb + cg);

  int tokCur[4] = {100, 100, 100, 100};

  for (int t = 0; t < NSTAGE; ++t) {
    const int u = t - l;
    const bool active = (u >= 0) && (u <= 256);
    const int rp = (t + 1) & 1;
    const int wp = t & 1;
    if (active) {
      if (l < 3) {
        // ---------------- GRU layer ----------------
        const int koff0 = (kh << 9) + (lq << 3);
        const u16* rowp[4];
        if (part == 0) {
          if (l == 0) {
            #pragma unroll
            for (int mi = 0; mi < 4; ++mi)
              rowp[mi] = emb16 + ((size_t)tokCur[mi] << 10) + koff0;
          } else {
            const u16* xb = hb16 + (((l - 1) * 2 + rp) << 16) + koff0;
            #pragma unroll
            for (int mi = 0; mi < 4; ++mi)
              rowp[mi] = xb + ((mi * 16 + ln) << 10);
          }
        } else {
          if (u == 0) {
            const u16* hb = ini16 + (l << 10) + koff0;
            #pragma unroll
            for (int mi = 0; mi < 4; ++mi) rowp[mi] = hb;
          } else {
            const u16* hb = hb16 + ((l * 2 + rp) << 16) + koff0;
            #pragma unroll
            for (int mi = 0; mi < 4; ++mi)
              rowp[mi] = hb + ((mi * 16 + ln) << 10);
          }
        }

        // next-stage token prefetch, fenced so it can't sink into the
        // counted-vmcnt window below
        int tokNext[4];
        const bool wantTok = (l == 0) && (part == 0) && (u < 256);
        if (wantTok) {
          #pragma unroll
          for (int mi = 0; mi < 4; ++mi)
            tokNext[mi] = y[((mi * 16 + ln) << 8) + u];
        }
        __builtin_amdgcn_sched_barrier(0);

        f4v acc[3][4];
        #pragma unroll
        for (int g = 0; g < 3; ++g)
          #pragma unroll
          for (int mi = 0; mi < 4; ++mi)
            acc[g][mi] = (f4v){0.f, 0.f, 0.f, 0.f};

        // prologue: issue rounds 0,1 (16 loads in flight)
        b8v fr[3][2][4];
        #pragma unroll
        for (int rr = 0; rr < 2; ++rr)
          #pragma unroll
          for (int tti = 0; tti < 2; ++tti)
            #pragma unroll
            for (int mi = 0; mi < 4; ++mi)
              fr[rr][tti][mi] = gload16(rowp[mi] + rr * 64 + tti * 32);

        gru_round<0, 16>(fr, rowp, wreg, acc);
        gru_round<1, 16>(fr, rowp, wreg, acc);
        gru_round<2, 16>(fr, rowp, wreg, acc);
        gru_round<3, 16>(fr, rowp, wreg, acc);
        gru_round<4, 16>(fr, rowp, wreg, acc);
        gru_round<5, 16>(fr, rowp, wreg, acc);
        gru_round<6, 8>(fr, rowp, wreg, acc);
        gru_round<7, 0>(fr, rowp, wreg, acc);

        #pragma unroll
        for (int g = 0; g < 3; ++g)
          #pragma unroll
          for (int mi = 0; mi < 4; ++mi)
            #pragma unroll
            for (int r4 = 0; r4 < 4; ++r4)
              gate_lds[wv * 3 + g][mi * 16 + lq * 4 + r4][ln] = acc[g][mi][r4];
        __syncthreads();

        {
          const f4v v0  = *(const f4v*)&gate_lds[0][eb][cc];
          const f4v v1  = *(const f4v*)&gate_lds[1][eb][cc];
          const f4v v2  = *(const f4v*)&gate_lds[2][eb][cc];
          const f4v v3  = *(const f4v*)&gate_lds[3][eb][cc];
          const f4v v4  = *(const f4v*)&gate_lds[4][eb][cc];
          const f4v v5  = *(const f4v*)&gate_lds[5][eb][cc];
          const f4v v6  = *(const f4v*)&gate_lds[6][eb][cc];
          const f4v v7  = *(const f4v*)&gate_lds[7][eb][cc];
          const f4v v8  = *(const f4v*)&gate_lds[8][eb][cc];
          const f4v v9  = *(const f4v*)&gate_lds[9][eb][cc];
          const f4v v10 = *(const f4v*)&gate_lds[10][eb][cc];
          const f4v v11 = *(const f4v*)&gate_lds[11][eb][cc];
          u16 pk[4];
          #pragma unroll
          for (int j = 0; j < 4; ++j) {
            float rg = sigm(v0[j] + v6[j] + v3[j] + v9[j] + rb[j]);
            float zg = sigm(v1[j] + v7[j] + v4[j] + v10[j] + zb[j]);
            float ng = tanh_f(v2[j] + v8[j] + ib[j] + rg * (v5[j] + v11[j] + hbv[j]));
            float hn = (1.0f - zg) * ng + zg * hold[j];
            hold[j] = hn;
            pk[j] = f2b(hn);
          }
          astore8(hb16 + ((l * 2 + wp) << 16) + (eb << 10) + cg,
                  pk[0], pk[1], pk[2], pk[3]);
        }
        if (wantTok) {
          #pragma unroll
          for (int mi = 0; mi < 4; ++mi) tokCur[mi] = tokNext[mi];
        }
      } else {
        // ---------------- output projection ----------------
        const u16* xb = hb16 + ((4 + rp) << 16) + (wv << 8) + (lq << 3);
        const u16* rowp[4];
        #pragma unroll
        for (int mi = 0; mi < 4; ++mi) rowp[mi] = xb + ((mi * 16 + ln) << 10);

        f4v acc[4];
        #pragma unroll
        for (int mi = 0; mi < 4; ++mi) acc[mi] = (f4v){0.f, 0.f, 0.f, 0.f};

        b8v fr[3][2][4];
        #pragma unroll
        for (int rr = 0; rr < 2; ++rr)
          #pragma unroll
          for (int tti = 0; tti < 2; ++tti)
            #pragma unroll
            for (int mi = 0; mi < 4; ++mi)
              fr[rr][tti][mi] = gload16(rowp[mi] + rr * 64 + tti * 32);

        prj_round<0, 16>(fr, rowp, wreg, acc);
        prj_round<1, 16>(fr, rowp, wreg, acc);
        prj_round<2, 8>(fr, rowp, wreg, acc);
        prj_round<3, 0>(fr, rowp, wreg, acc);

        #pragma unroll
        for (int mi = 0; mi < 4; ++mi)
          #pragma unroll
          for (int r4 = 0; r4 < 4; ++r4)
            gate_lds[wv][mi * 16 + lq * 4 + r4][ln] = acc[mi][r4];
        __syncthreads();

        {
          const f4v s0 = *(const f4v*)&gate_lds[0][eb][cc];
          const f4v s1 = *(const f4v*)&gate_lds[1][eb][cc];
          const f4v s2 = *(const f4v*)&gate_lds[2][eb][cc];
          const f4v s3 = *(const f4v*)&gate_lds[3][eb][cc];
          f4v v = s0 + s1 + s2 + s3 + pbias;
          *(f4v*)(out + (((size_t)(eb * 257 + u)) << 10) + cg) = v;
        }
      }
    }

    // ---- two-level tree barrier (skip after last stage) ----
    // __syncthreads drains vmcnt -> all sc1 data stores are at the coherence
    // point before the arrival RMW. Counters monotonic; last arriver forwards.
    if (t + 1 < NSTAGE) {
      __syncthreads();
      if (tid == 0) {
        const int tgt = t + 1;
        int old = __hip_atomic_fetch_add(myarr, 1, __ATOMIC_RELAXED,
                                         __HIP_MEMORY_SCOPE_AGENT);
        if (old + 1 == (tgt << 4)) {          // last of my 16-block group
          int gold = __hip_atomic_fetch_add(gctr, 1, __ATOMIC_RELAXED,
                                            __HIP_MEMORY_SCOPE_AGENT);
          if (gold + 1 == (tgt << 4)) {       // last group overall
            #pragma unroll
            for (int r = 0; r < 16; ++r)
              st_i((int*)(relb + (size_t)r * 256), tgt);
          }
        }
        while (ld_i(myrel) < tgt) __builtin_amdgcn_s_sleep(2);
      }
      __syncthreads();
    }
  }
}

// ---------------- slow fallback (round-3 passing kernel) ----------------
__global__ __launch_bounds__(256) void dec_slow(
    const int* __restrict__ y, const float* __restrict__ embed,
    const float* __restrict__ Wih, const float* __restrict__ Whh,
    const float* __restrict__ bih, const float* __restrict__ bhh,
    const float* __restrict__ initS, const float* __restrict__ linW,
    const float* __restrict__ linb, float* __restrict__ out,
    unsigned char* __restrict__ ws)
{
  cg::grid_group grid = cg::this_grid();
  __shared__ b8v a_lds[2048];
  __shared__ float gate_lds[4][64][17];
  __shared__ int tok_lds[64];
  const int tid = threadIdx.x, bid = blockIdx.x;
  const int l = bid >> 6, c0 = (bid & 63) << 4;
  const int wv = tid >> 6, lane = tid & 63, lq = lane >> 4, ln = lane & 15;
  float* hb32 = (float*)ws;
  const int rowoff = (wv == 0) ? c0 : (wv == 1) ? (1024 + c0) : (2048 + c0);
  const size_t wl = (size_t)(l < 3 ? l : 0) * 3072 * 1024;
  const float* WihL = Wih + wl;
  const float* WhhL = Whh + wl;
  for (int t = 0; t < NSTAGE; ++t) {
    const int u = t - l;
    const bool active = (u >= 0) && (u <= 256);
    const int rp = (t + 1) & 1, wp = t & 1;
    if (active) {
      if (l == 0 && tid < 64)
        tok_lds[tid] = (u == 0) ? 100 : y[(tid << 8) + (u - 1)];
      if (l < 3) {
        f4v acc[4];
        #pragma unroll
        for (int mi = 0; mi < 4; ++mi) acc[mi] = (f4v){0.f, 0.f, 0.f, 0.f};
        const float* xbase = (l == 0) ? embed : (hb32 + (((l - 1) * 2 + rp) << 16));
        const float* hbase = hb32 + ((l * 2 + rp) << 16);
        for (int s = 0; s < 8; ++s) {
          __syncthreads();
          #pragma unroll
          for (int i = 0; i < 8; ++i) {
            int g = tid + (i << 8);
            int sec = g >> 10, gg = g & 1023, b = gg & 63, k8 = gg >> 6;
            int koff = (s << 7) + (k8 << 3);
            const float* src;
            if (sec == 0) src = (l == 0) ? embed + ((size_t)tok_lds[b] << 10) + koff
                                         : xbase + (b << 10) + koff;
            else src = (u == 0) ? initS + (l << 10) + koff : hbase + (b << 10) + koff;
            a_lds[((sec << 4) + k8) * 64 + b] = cvt8(*(const f4v*)src, *(const f4v*)(src + 4));
          }
          __syncthreads();
          const int pstart = (wv == 3) ? 1 : 0;
          const int pend = (wv == 2) ? 1 : 2;
          for (int part = pstart; part < pend; ++part) {
            const float* wrow = ((part == 0) ? WihL : WhhL)
                              + (size_t)(rowoff + ln) * 1024 + (s << 7) + (lq << 3);
            #pragma unroll
            for (int tt = 0; tt < 4; ++tt) {
              b8v bf = cvt8(*(const f4v*)(wrow + (tt << 5)), *(const f4v*)(wrow + (tt << 5) + 4));
              int fb = ((part << 4) + (tt << 2) + lq) * 64 + ln;
              #pragma unroll
              for (int mi = 0; mi < 4; ++mi)
                acc[mi] = __builtin_amdgcn_mfma_f32_16x16x32_bf16(a_lds[fb + (mi << 4)], bf, acc[mi], 0, 0, 0);
            }
          }
        }
        #pragma unroll
        for (int mi = 0; mi < 4; ++mi)
          #pragma unroll
          for (int r = 0; r < 4; ++r)
            gate_lds[wv][(mi << 4) + (lq << 2) + r][ln] = acc[mi][r];
        __syncthreads();
        {
          const int b = tid >> 2, cc = (tid & 3) << 2, cg = c0 + cc;
          const float* biL = bih + l * 3072;
          const float* bhL = bhh + l * 3072;
          float hold[4];
          if (u == 0) {
            #pragma unroll
            for (int j = 0; j < 4; ++j) hold[j] = initS[(l << 10) + cg + j];
          } else {
            const float* hp = hb32 + ((size_t)(l * 2 + rp) << 16) + (b << 10) + cg;
            #pragma unroll
            for (int j = 0; j < 4; ++j) hold[j] = hp[j];
          }
          float* o32 = hb32 + ((size_t)(l * 2 + wp) << 16) + (b << 10) + cg;
          #pragma unroll
          for (int j = 0; j < 4; ++j) {
            int c = cg + j;
            float rpre = gate_lds[0][b][cc + j] + biL[c] + bhL[c];
            float zpre = gate_lds[1][b][cc + j] + biL[1024 + c] + bhL[1024 + c];
            float inn = gate_lds[2][b][cc + j] + biL[2048 + c];
            float hnn = gate_lds[3][b][cc + j] + bhL[2048 + c];
            float rg = sigm(rpre), zg = sigm(zpre);
            float ng = tanh_f(inn + rg * hnn);
            o32[j] = (1.0f - zg) * ng + zg * hold[j];
          }
        }
      } else {
        f4v acc1 = (f4v){0.f, 0.f, 0.f, 0.f};
        const float* xbase = hb32 + ((4 + rp) << 16);
        for (int s = 0; s < 8; ++s) {
          __syncthreads();
          #pragma unroll
          for (int i = 0; i < 4; ++i) {
            int g = tid + (i << 8);
            int b = g & 63, k8 = g >> 6;
            const float* src = xbase + (b << 10) + (s << 7) + (k8 << 3);
            a_lds[k8 * 64 + b] = cvt8(*(const f4v*)src, *(const f4v*)(src + 4));
          }
          __syncthreads();
          const float* wrow = linW + (size_t)(c0 + ln) * 1024 + (s << 7) + (lq << 3);
          #pragma unroll
          for (int tt = 0; tt < 4; ++tt) {
            b8v bf = cvt8(*(const f4v*)(wrow + (tt << 5)), *(const f4v*)(wrow + (tt << 5) + 4));
            acc1 = __builtin_amdgcn_mfma_f32_16x16x32_bf16(
                     a_lds[((tt << 2) + lq) * 64 + (wv << 4) + ln], bf, acc1, 0, 0, 0);
          }
        }
        const float bias = linb[c0 + ln];
        #pragma unroll
        for (int r = 0; r < 4; ++r) {
          int b = (wv << 4) + (lq << 2) + r;
          out[((size_t)(b * 257 + u) << 10) + c0 + ln] = acc1[r] + bias;
        }
      }
    }
    grid.sync();
  }
}

extern "C" void kernel_launch(void* const* d_in, const int* in_sizes, int n_in,
                              void* d_out, int out_size, void* d_ws, size_t ws_size,
                              hipStream_t stream) {
  const int* y        = (const int*)d_in[0];
  const float* embed  = (const float*)d_in[2];
  const float* Wih    = (const float*)d_in[3];
  const float* Whh    = (const float*)d_in[4];
  const float* bih    = (const float*)d_in[5];
  const float* bhh    = (const float*)d_in[6];
  const float* initS  = (const float*)d_in[7];
  const float* linW   = (const float*)d_in[8];
  const float* linb   = (const float*)d_in[9];
  float* out = (float*)d_out;
  unsigned char* ws = (unsigned char*)d_ws;

  if (ws_size >= WS_NEED) {
    // Fast path: regular launches only — identical behavior in fresh,
    // capture, and replay modes (no cooperative API anywhere).
    hipLaunchKernelGGL(prep, dim3(N_TOT_GRP / 256), dim3(256), 0, stream,
                       embed, Wih, Whh, initS, linW, ws);
    hipLaunchKernelGGL(dec_fast, dim3(NB), dim3(256), 0, stream,
                       y, bih, bhh, initS, linb, out, ws);
  } else {
    void* args[] = {(void*)&y, (void*)&embed, (void*)&Wih, (void*)&Whh,
                    (void*)&bih, (void*)&bhh, (void*)&initS, (void*)&linW,
                    (void*)&linb, (void*)&out, (void*)&ws};
    hipLaunchCooperativeKernel((void*)dec_slow, dim3(NB), dim3(256), args, 0, stream);
  }
}